// Round 7
// baseline (4169.556 us; speedup 1.0000x reference)
//
#include <hip/hip_runtime.h>
#include <math.h>

// ---------------- problem constants ----------------
constexpr int NB = 32;    // B
constexpr int NM = 64;    // M
constexpr int NNV = 65;   // NV
constexpr int NH = 960;   // H
constexpr int ND = 480;   // D
constexpr float ATT_SCALE = 0.045643546458763842f;  // D^-0.5

constexpr int OF_Pq = 0;
constexpr int OF_cq = 4320;
constexpr int OF_Q2 = 5760;
constexpr int OF_V2 = OF_Q2 + 2*1440;
constexpr int OF_dq = 10080;
constexpr int OF_dv = OF_dq + 2*480;
constexpr int OF_S  = 11520;
constexpr int OF_u  = 11529;
constexpr int OF_r  = 11532;
constexpr int OF_w  = 11535;
constexpr int FOLD_SZ = 11552;

typedef unsigned short u16;
typedef float f32x4 __attribute__((ext_vector_type(4)));
typedef short s16x8 __attribute__((ext_vector_type(8)));

__device__ __forceinline__ float wave_sum(float v) {
#pragma unroll
  for (int d = 32; d; d >>= 1) v += __shfl_xor(v, d);
  return v;
}

__device__ __forceinline__ void split_bf16(float x, short& hi, short& lo) {
  union { float f; unsigned u; } a; a.f = x;
  unsigned uh = a.u + 0x7fffu + ((a.u >> 16) & 1u);
  hi = (short)(uh >> 16);
  union { unsigned u; float f; } b; b.u = ((unsigned)(unsigned short)hi) << 16;
  union { float f; unsigned u; } c; c.f = x - b.f;
  unsigned ul = c.u + 0x7fffu + ((c.u >> 16) & 1u);
  lo = (short)(ul >> 16);
}

__device__ __forceinline__ float join_bf16(u16 h, u16 l) {
  union { unsigned u; float f; } a, b;
  a.u = ((unsigned)h) << 16; b.u = ((unsigned)l) << 16;
  return a.f + b.f;
}

// transpose-convert: dst[z][n][k] = split(src[z][k][n]) for 5 planes (bt_W 0..2, bi_W 0..1)
__global__ __launch_bounds__(256) void k_cvtT(
    const float* __restrict__ btW, const float* __restrict__ biW,
    u16* __restrict__ wtHi, u16* __restrict__ wtLo)
{
  __shared__ float s[32][33];
  const int z = blockIdx.z;
  const float* src = (z < 3) ? (btW + (size_t)z * ND * ND) : (biW + (size_t)(z - 3) * ND * ND);
  u16* dh = wtHi + (size_t)z * ND * ND;
  u16* dl = wtLo + (size_t)z * ND * ND;
  const int k0 = blockIdx.y * 32, n0 = blockIdx.x * 32;
  const int tx = threadIdx.x & 31, ty = threadIdx.x >> 5;
#pragma unroll
  for (int q = 0; q < 4; ++q)
    s[ty + q * 8][tx] = src[(size_t)(k0 + ty + q * 8) * ND + n0 + tx];
  __syncthreads();
#pragma unroll
  for (int q = 0; q < 4; ++q) {
    float v = s[tx][ty + q * 8];
    short h, l; split_bf16(v, h, l);
    size_t di = (size_t)(n0 + ty + q * 8) * ND + k0 + tx;
    dh[di] = (u16)h; dl[di] = (u16)l;
  }
}

// ---------------- MFMA projection GEMM (round-5 style on-fly split) + plane epilogue ----------------
struct ProjCfg {
  const float* X; const float* W; const float* bias; float* C;
  u16* pH; u16* pL;
  int R; int x0; int rpb; int xbs;
};
struct Proj6 { ProjCfg c[6]; };

constexpr int KP = 40;   // padded k stride (ushorts)

__global__ __launch_bounds__(256) void k_projM(Proj6 P, int K)
{
  __shared__ u16 As_hi[64][KP], As_lo[64][KP];
  __shared__ u16 Bs_hi[48][KP], Bs_lo[48][KP];
  int p = blockIdx.x, total = gridDim.x;
  int q = total >> 3, r = total & 7;
  int xk = p & 7, idx = p >> 3;
  int lgc = (xk < r) ? (xk * (q + 1) + idx) : (r * (q + 1) + (xk - r) * q + idx);
  int mp = lgc / 10, nx = lgc - mp * 10;
  ProjCfg cfg; int my;
  if      (mp < 32)  { cfg = P.c[0]; my = mp; }
  else if (mp < 65)  { cfg = P.c[1]; my = mp - 32; }
  else if (mp < 97)  { cfg = P.c[2]; my = mp - 65; }
  else if (mp < 129) { cfg = P.c[3]; my = mp - 97; }
  else if (mp < 161) { cfg = P.c[4]; my = mp - 129; }
  else               { cfg = P.c[5]; my = mp - 161; }
  const int m0 = my * 64, n0 = nx * 48;
  const int tid = threadIdx.x;
  const int l6 = tid & 63, w = tid >> 6;
  const int lr = tid >> 2, kc = (tid & 3) * 8;
  const float* Arow = nullptr;
  {
    int rr = m0 + lr;
    if (rr < cfg.R) {
      int b = rr / cfg.rpb, r2 = rr - b * cfg.rpb;
      Arow = cfg.X + (size_t)b * cfg.xbs + (size_t)(cfg.x0 + r2) * K;
    }
  }
  const float* Brow = (lr < 48) ? (cfg.W + (size_t)(n0 + lr) * K) : nullptr;
  const int fr = l6 & 15, fk = (l6 >> 4) * 8;
  f32x4 acc0 = {0.f, 0.f, 0.f, 0.f}, acc1 = acc0, acc2 = acc0;
  for (int k0 = 0; k0 < K; k0 += 32) {
    float xs[8] = {0.f, 0.f, 0.f, 0.f, 0.f, 0.f, 0.f, 0.f};
    if (Arow) {
      float4 a0 = *(const float4*)(Arow + k0 + kc);
      float4 a1 = *(const float4*)(Arow + k0 + kc + 4);
      xs[0] = a0.x; xs[1] = a0.y; xs[2] = a0.z; xs[3] = a0.w;
      xs[4] = a1.x; xs[5] = a1.y; xs[6] = a1.z; xs[7] = a1.w;
    }
    s16x8 vh, vl;
#pragma unroll
    for (int e = 0; e < 8; ++e) { short h, lo2; split_bf16(xs[e], h, lo2); vh[e] = h; vl[e] = lo2; }
    *(s16x8*)&As_hi[lr][kc] = vh;
    *(s16x8*)&As_lo[lr][kc] = vl;
    if (Brow) {
      float4 b0 = *(const float4*)(Brow + k0 + kc);
      float4 b1 = *(const float4*)(Brow + k0 + kc + 4);
      float ys[8] = {b0.x, b0.y, b0.z, b0.w, b1.x, b1.y, b1.z, b1.w};
      s16x8 wh, wl;
#pragma unroll
      for (int e = 0; e < 8; ++e) { short h, lo2; split_bf16(ys[e], h, lo2); wh[e] = h; wl[e] = lo2; }
      *(s16x8*)&Bs_hi[lr][kc] = wh;
      *(s16x8*)&Bs_lo[lr][kc] = wl;
    }
    __syncthreads();
    s16x8 ah = *(const s16x8*)&As_hi[16 * w + fr][fk];
    s16x8 al = *(const s16x8*)&As_lo[16 * w + fr][fk];
    {
      s16x8 bh = *(const s16x8*)&Bs_hi[fr][fk];
      s16x8 bl = *(const s16x8*)&Bs_lo[fr][fk];
      acc0 = __builtin_amdgcn_mfma_f32_16x16x32_bf16(ah, bh, acc0, 0, 0, 0);
      acc0 = __builtin_amdgcn_mfma_f32_16x16x32_bf16(ah, bl, acc0, 0, 0, 0);
      acc0 = __builtin_amdgcn_mfma_f32_16x16x32_bf16(al, bh, acc0, 0, 0, 0);
    }
    {
      s16x8 bh = *(const s16x8*)&Bs_hi[16 + fr][fk];
      s16x8 bl = *(const s16x8*)&Bs_lo[16 + fr][fk];
      acc1 = __builtin_amdgcn_mfma_f32_16x16x32_bf16(ah, bh, acc1, 0, 0, 0);
      acc1 = __builtin_amdgcn_mfma_f32_16x16x32_bf16(ah, bl, acc1, 0, 0, 0);
      acc1 = __builtin_amdgcn_mfma_f32_16x16x32_bf16(al, bh, acc1, 0, 0, 0);
    }
    {
      s16x8 bh = *(const s16x8*)&Bs_hi[32 + fr][fk];
      s16x8 bl = *(const s16x8*)&Bs_lo[32 + fr][fk];
      acc2 = __builtin_amdgcn_mfma_f32_16x16x32_bf16(ah, bh, acc2, 0, 0, 0);
      acc2 = __builtin_amdgcn_mfma_f32_16x16x32_bf16(ah, bl, acc2, 0, 0, 0);
      acc2 = __builtin_amdgcn_mfma_f32_16x16x32_bf16(al, bh, acc2, 0, 0, 0);
    }
    __syncthreads();
  }
#pragma unroll
  for (int c = 0; c < 3; ++c) {
    f32x4 av = (c == 0) ? acc0 : (c == 1) ? acc1 : acc2;
    int n = n0 + 16 * c + fr;
    float bv = cfg.bias[n];
#pragma unroll
    for (int g = 0; g < 4; ++g) {
      int rr = m0 + 16 * w + (l6 >> 4) * 4 + g;
      if (rr < cfg.R) {
        float v = av[g] + bv;
        size_t di = (size_t)rr * ND + n;
        cfg.C[di] = v;
        if (cfg.pH) {
          short h, lo2; split_bf16(v, h, lo2);
          cfg.pH[di] = (u16)h; cfg.pL[di] = (u16)lo2;
        }
      }
    }
  }
}

// ================= MEGA: full 5-round loop per batch b =================
template <int O, int NVX>
__global__ __launch_bounds__(1024, 4) void k_mega(
    const u16* __restrict__ WtH, const u16* __restrict__ WtL,   // [O][480][480] (n,k)
    u16* __restrict__ tmpH, u16* __restrict__ tmpL,             // [NB][O][64][480]
    u16* __restrict__ keyH, u16* __restrict__ keyL,             // [NB][64][480]
    u16* __restrict__ valH, u16* __restrict__ valL,             // [NB][NVX][480]
    const float* __restrict__ kmp, const float* __restrict__ vmp, int vmOff, int vmStride,
    const float* __restrict__ F, const float* __restrict__ lw, const float* __restrict__ lb,
    const float* __restrict__ linK0, const float* __restrict__ linV0,
    float* __restrict__ outp)
{
  constexpr int NT = (NVX + 15) >> 4;
  __shared__ float Lb[NM][NVX][3];
  __shared__ float Yb[NM][NVX][3];
  __shared__ float linKL[NM][3];
  __shared__ float linVL[NVX][3];
  __shared__ float kmL[NM];
  __shared__ float vmL[NVX];
  const int b = blockIdx.x;
  const int tid = threadIdx.x;
  const int w = tid >> 6, l = tid & 63;
  const int fr = l & 15, fko = (l >> 4) * 8;
  const int rquad = (l >> 4) * 4;

  if (tid < NM) {
    kmL[tid] = kmp[b * NM + tid];
#pragma unroll
    for (int o = 0; o < O; ++o) linKL[tid][o] = linK0[(size_t)(b * NM + tid) * O + o];
  } else if (tid >= 128 && tid - 128 < NVX) {
    int n = tid - 128;
    vmL[n] = vmp[b * vmStride + vmOff + n];
#pragma unroll
    for (int o = 0; o < O; ++o) linVL[n][o] = linV0[(size_t)(b * NVX + n) * O + o];
  }
  float SmA[9], SmB[9];
#pragma unroll
  for (int s = 0; s < 9; ++s) { SmA[s] = F[OF_S + s]; SmB[s] = F[OF_S + 16 + s]; }
  float uA[3], uB[3], rA[3], rB[3];
#pragma unroll
  for (int s = 0; s < 3; ++s) {
    uA[s] = F[OF_u + s]; uB[s] = F[OF_u + 16 + s];
    rA[s] = F[OF_r + s]; rB[s] = F[OF_r + 16 + s];
  }
  const float wA = F[OF_w], wB = F[OF_w + 16];
  const float* V2 = F + OF_V2;
  const float* dvp = F + OF_dv;

  const size_t bK = (size_t)b * NM * ND;
  const size_t bV = (size_t)b * NVX * ND;
  u16* tH = tmpH + (size_t)b * O * NM * ND;
  u16* tL = tmpL + (size_t)b * O * NM * ND;
  const u16* kHb = keyH + bK; const u16* kLb = keyL + bK;
  const u16* vHb = valH + bV; const u16* vLb = valL + bV;
  const s16x8 zf = {0, 0, 0, 0, 0, 0, 0, 0};

  for (int r = 0; r < 5; ++r) {
    __syncthreads();
    // ---- G: tmp[o][m][n] = key @ W[o] (MFMA, direct-global frags) ----
    {
      const int GJ = O * 30;
      for (int t = w; t < GJ; t += 16) {
        int o = t / 30, nt = t - o * 30;
        const u16* bH = WtH + ((size_t)o * ND + nt * 16 + fr) * ND + fko;
        const u16* bL2 = WtL + ((size_t)o * ND + nt * 16 + fr) * ND + fko;
        f32x4 z4 = {0.f, 0.f, 0.f, 0.f};
        f32x4 am[4] = {z4, z4, z4, z4};
#pragma unroll 3
        for (int k0 = 0; k0 < ND; k0 += 32) {
          s16x8 bh = *(const s16x8*)(bH + k0);
          s16x8 bl = *(const s16x8*)(bL2 + k0);
#pragma unroll
          for (int mt = 0; mt < 4; ++mt) {
            s16x8 ah = *(const s16x8*)(kHb + (size_t)(mt * 16 + fr) * ND + fko + k0);
            s16x8 al = *(const s16x8*)(kLb + (size_t)(mt * 16 + fr) * ND + fko + k0);
            am[mt] = __builtin_amdgcn_mfma_f32_16x16x32_bf16(ah, bh, am[mt], 0, 0, 0);
            am[mt] = __builtin_amdgcn_mfma_f32_16x16x32_bf16(ah, bl, am[mt], 0, 0, 0);
            am[mt] = __builtin_amdgcn_mfma_f32_16x16x32_bf16(al, bh, am[mt], 0, 0, 0);
          }
        }
        int n = nt * 16 + fr;
#pragma unroll
        for (int mt = 0; mt < 4; ++mt)
#pragma unroll
          for (int g = 0; g < 4; ++g) {
            int m = mt * 16 + rquad + g;
            short h, lo2; split_bf16(am[mt][g], h, lo2);
            size_t di = ((size_t)o * NM + m) * ND + n;
            tH[di] = (u16)h; tL[di] = (u16)lo2;
          }
      }
    }
    __syncthreads();
    // ---- BIL: L[m][n][o] = tmp[o] @ val^T + linK + linV + lb ----
    const bool finalr = (r == 4);
    {
      const int BJ = O * NT;
      for (int t = w; t < BJ; t += 16) {
        int o = t / NT, nt = t - o * NT;
        int n = nt * 16 + fr;
        bool nok = n < NVX;
        const u16* bH = vHb + (size_t)(nok ? n : 0) * ND + fko;
        const u16* bL2 = vLb + (size_t)(nok ? n : 0) * ND + fko;
        f32x4 z4 = {0.f, 0.f, 0.f, 0.f};
        f32x4 am[4] = {z4, z4, z4, z4};
#pragma unroll 3
        for (int k0 = 0; k0 < ND; k0 += 32) {
          s16x8 bh = nok ? *(const s16x8*)(bH + k0) : zf;
          s16x8 bl = nok ? *(const s16x8*)(bL2 + k0) : zf;
#pragma unroll
          for (int mt = 0; mt < 4; ++mt) {
            s16x8 ah = *(const s16x8*)(tH + ((size_t)o * NM + mt * 16 + fr) * ND + fko + k0);
            s16x8 al = *(const s16x8*)(tL + ((size_t)o * NM + mt * 16 + fr) * ND + fko + k0);
            am[mt] = __builtin_amdgcn_mfma_f32_16x16x32_bf16(ah, bh, am[mt], 0, 0, 0);
            am[mt] = __builtin_amdgcn_mfma_f32_16x16x32_bf16(ah, bl, am[mt], 0, 0, 0);
            am[mt] = __builtin_amdgcn_mfma_f32_16x16x32_bf16(al, bh, am[mt], 0, 0, 0);
          }
        }
        if (nok) {
          float lbo = lb[o];
#pragma unroll
          for (int mt = 0; mt < 4; ++mt)
#pragma unroll
            for (int g = 0; g < 4; ++g) {
              int m = mt * 16 + rquad + g;
              float v = am[mt][g] + linKL[m][o] + linVL[n][o] + lbo;
              if (!finalr) Lb[m][n][o] = v;
              else outp[(((size_t)b * NM + m) * NVX + n) * O + o] = v * kmL[m] * vmL[n];
            }
        }
      }
    }
    if (finalr) break;
    __syncthreads();
    // ---- att0 (per (m,i), online softmax over NV axis) -> Yb ----
    for (int job = tid; job < NM * NVX; job += 1024) {
      int m = job / NVX, i = job - m * NVX;
      float Li0 = Lb[m][i][0], Li1 = Lb[m][i][1], Li2 = (O == 3) ? Lb[m][i][2] : 0.f;
      float st0 = Li0 * SmA[0] + Li1 * SmA[3] + Li2 * SmA[6];
      float st1 = Li0 * SmA[1] + Li1 * SmA[4] + Li2 * SmA[7];
      float st2 = Li0 * SmA[2] + Li1 * SmA[5] + Li2 * SmA[8];
      float hi = Li0 * uA[0] + Li1 * uA[1] + Li2 * uA[2];
      bool rowz = (kmL[m] == 0.f) || (vmL[i] == 0.f);
      float mx = -3.0e38f, sum = 0.f, y0 = 0.f, y1 = 0.f, y2 = 0.f;
      for (int j = 0; j < NVX; ++j) {
        float t0 = Lb[m][j][0], t1 = Lb[m][j][1], t2 = (O == 3) ? Lb[m][j][2] : 0.f;
        float s = st0 * t0 + st1 * t1 + st2 * t2 + hi
                + (t0 * rA[0] + t1 * rA[1] + t2 * rA[2]) + wA;
        s = (rowz || vmL[j] == 0.f) ? -10000.f : ATT_SCALE * s;
        float nm = fmaxf(mx, s);
        float p = __expf(s - nm), cc = __expf(mx - nm);
        sum = sum * cc + p; y0 = y0 * cc + p * t0; y1 = y1 * cc + p * t1; y2 = y2 * cc + p * t2;
        mx = nm;
      }
      float inv = 1.f / sum;
      Yb[m][i][0] = y0 * inv; Yb[m][i][1] = y1 * inv;
      if (O == 3) Yb[m][i][2] = y2 * inv;
    }
    __syncthreads();
    // ---- att1 (per (n,i), over M axis) -> Y2 into Lb[i][n] ----
    for (int job = tid; job < NVX * NM; job += 1024) {
      int n = job / NM, i = job - n * NM;
      float Yi0 = Yb[i][n][0], Yi1 = Yb[i][n][1], Yi2 = (O == 3) ? Yb[i][n][2] : 0.f;
      float st0 = Yi0 * SmB[0] + Yi1 * SmB[3] + Yi2 * SmB[6];
      float st1 = Yi0 * SmB[1] + Yi1 * SmB[4] + Yi2 * SmB[7];
      float st2 = Yi0 * SmB[2] + Yi1 * SmB[5] + Yi2 * SmB[8];
      float hi = Yi0 * uB[0] + Yi1 * uB[1] + Yi2 * uB[2];
      bool rowz = (vmL[n] == 0.f) || (kmL[i] == 0.f);
      float mx = -3.0e38f, sum = 0.f, y0 = 0.f, y1 = 0.f, y2 = 0.f;
      for (int j = 0; j < NM; ++j) {
        float t0 = Yb[j][n][0], t1 = Yb[j][n][1], t2 = (O == 3) ? Yb[j][n][2] : 0.f;
        float s = st0 * t0 + st1 * t1 + st2 * t2 + hi
                + (t0 * rB[0] + t1 * rB[1] + t2 * rB[2]) + wB;
        s = (rowz || kmL[j] == 0.f) ? -10000.f : ATT_SCALE * s;
        float nm = fmaxf(mx, s);
        float p = __expf(s - nm), cc = __expf(mx - nm);
        sum = sum * cc + p; y0 = y0 * cc + p * t0; y1 = y1 * cc + p * t1; y2 = y2 * cc + p * t2;
        mx = nm;
      }
      float inv = 1.f / sum;
      Lb[i][n][0] = y0 * inv; Lb[i][n][1] = y1 * inv;
      if (O == 3) Lb[i][n][2] = y2 * inv;
    }
    __syncthreads();
    // ---- vupd (per (n,4d)) + kupd (per (m,4d)); Y2 is in Lb ----
    for (int u = tid; u < (NVX + NM) * 120; u += 1024) {
      if (u < NVX * 120) {
        int n = u / 120, dg = u - n * 120; int d0 = dg * 4;
        float v0[4], v1[4], v2[4], dl4[4];
#pragma unroll
        for (int e = 0; e < 4; ++e) {
          v0[e] = V2[d0 + e]; v1[e] = V2[ND + d0 + e];
          v2[e] = (O == 3) ? V2[2 * ND + d0 + e] : 0.f;
          dl4[e] = dvp[d0 + e];
        }
        float mx[4] = {-3.0e38f, -3.0e38f, -3.0e38f, -3.0e38f};
        for (int j = 0; j < NM; ++j) {
          float y0 = Lb[j][n][0], y1 = Lb[j][n][1], y2 = (O == 3) ? Lb[j][n][2] : 0.f;
#pragma unroll
          for (int e = 0; e < 4; ++e)
            mx[e] = fmaxf(mx[e], y0 * v0[e] + y1 * v1[e] + y2 * v2[e]);
        }
        float p0 = 0.f, p1 = 0.f, p2 = 0.f;
#pragma unroll
        for (int e = 0; e < 4; ++e) {
          float delta = mx[e] + dl4[e];
          size_t gi = bV + (size_t)n * ND + d0 + e;
          float nv = join_bf16(valH[gi], valL[gi]) + delta;
          short h, lo2; split_bf16(nv, h, lo2);
          valH[gi] = (u16)h; valL[gi] = (u16)lo2;
          p0 += delta * lw[ND + d0 + e];
          p1 += delta * lw[2 * ND + ND + d0 + e];
          if (O == 3) p2 += delta * lw[4 * ND + ND + d0 + e];
        }
        atomicAdd(&linVL[n][0], p0);
        atomicAdd(&linVL[n][1], p1);
        if (O == 3) atomicAdd(&linVL[n][2], p2);
      } else {
        int u2 = u - NVX * 120;
        int m = u2 / 120, dg = u2 - m * 120; int d0 = dg * 4;
        float v0[4], v1[4], v2[4], dl4[4];
#pragma unroll
        for (int e = 0; e < 4; ++e) {
          v0[e] = V2[d0 + e]; v1[e] = V2[ND + d0 + e];
          v2[e] = (O == 3) ? V2[2 * ND + d0 + e] : 0.f;
          dl4[e] = dvp[d0 + e];
        }
        float mx[4] = {-3.0e38f, -3.0e38f, -3.0e38f, -3.0e38f};
        for (int j = 0; j < NVX; ++j) {
          float y0 = Lb[m][j][0], y1 = Lb[m][j][1], y2 = (O == 3) ? Lb[m][j][2] : 0.f;
#pragma unroll
          for (int e = 0; e < 4; ++e)
            mx[e] = fmaxf(mx[e], y0 * v0[e] + y1 * v1[e] + y2 * v2[e]);
        }
        float p0 = 0.f, p1 = 0.f, p2 = 0.f;
#pragma unroll
        for (int e = 0; e < 4; ++e) {
          float delta = mx[e] + dl4[e];
          size_t gi = bK + (size_t)m * ND + d0 + e;
          float nv = join_bf16(keyH[gi], keyL[gi]) + delta;
          short h, lo2; split_bf16(nv, h, lo2);
          keyH[gi] = (u16)h; keyL[gi] = (u16)lo2;
          p0 += delta * lw[d0 + e];
          p1 += delta * lw[2 * ND + d0 + e];
          if (O == 3) p2 += delta * lw[4 * ND + d0 + e];
        }
        atomicAdd(&linKL[m][0], p0);
        atomicAdd(&linKL[m][1], p1);
        if (O == 3) atomicAdd(&linKL[m][2], p2);
      }
    }
  }
}

// batched small matvec: Out[r,o] = X[r,:]·W[o, wOff:wOff+480]
struct SpCfg { const float* X; const float* W; float* Out; int R; int O; int wStride; int wOff; };
__global__ __launch_bounds__(256) void k_sproj6(
    SpCfg s0, SpCfg s1, SpCfg s2, SpCfg s3, SpCfg s4, SpCfg s5)
{
  int z = blockIdx.y;
  SpCfg c = (z == 0) ? s0 : (z == 1) ? s1 : (z == 2) ? s2 : (z == 3) ? s3 : (z == 4) ? s4 : s5;
  int gid = blockIdx.x * 4 + (threadIdx.x >> 6);
  if (gid >= c.R * c.O) return;
  int lane = threadIdx.x & 63;
  int r = gid / c.O, o = gid - r * c.O;
  const float* x = c.X + (size_t)r * ND;
  const float* wp = c.W + (size_t)o * c.wStride + c.wOff;
  float acc = 0.f;
  for (int d = lane; d < ND; d += 64) acc += x[d] * wp[d];
  acc = wave_sum(acc);
  if (lane == 0) c.Out[gid] = acc;
}

// ---------------- folds ----------------
struct FoldCfg { const float* fw; const float* fb; const float* qw; const float* qb; float* F; int O; };

__global__ __launch_bounds__(256) void k_fold1B(FoldCfg A, FoldCfg Bc)
{
  FoldCfg c = (blockIdx.y == 0) ? A : Bc;
  int O = c.O;
  int gid = blockIdx.x * 4 + (threadIdx.x >> 6);
  int lane = threadIdx.x & 63;
  if (gid >= 3 * ND) return;
  int part = gid / ND, cc0 = gid - part * ND;
  const float* qrow = c.qw + (size_t)(part * ND + cc0) * ND;
  float p0 = 0.f, p1 = 0.f, p2 = 0.f, cc = 0.f;
  for (int d = lane; d < ND; d += 64) {
    float q = qrow[d];
    p0 += c.fw[d * O + 0] * q;
    p1 += c.fw[d * O + 1] * q;
    if (O == 3) p2 += c.fw[d * O + 2] * q;
    cc += c.fb[d] * q;
  }
  p0 = wave_sum(p0); p1 = wave_sum(p1); p2 = wave_sum(p2); cc = wave_sum(cc);
  if (lane == 0) {
    c.F[OF_Pq + part * 1440 + 0 * ND + cc0] = p0;
    c.F[OF_Pq + part * 1440 + 1 * ND + cc0] = p1;
    c.F[OF_Pq + part * 1440 + 2 * ND + cc0] = (O == 3) ? p2 : 0.f;
    c.F[OF_cq + part * ND + cc0] = cc + c.qb[part * ND + cc0];
  }
}

__global__ __launch_bounds__(256) void k_fold2B(FoldCfg A, FoldCfg Bc)
{
  FoldCfg c = (blockIdx.y == 0) ? A : Bc;
  int O = c.O;
  float* F = c.F;
  int gid = blockIdx.x * 4 + (threadIdx.x >> 6);
  int lane = threadIdx.x & 63;
  if (gid < 3 * ND) {
    int part = gid / ND, cc0 = gid - part * ND;
    const float* qrow = c.qw + (size_t)(part * ND + cc0) * ND;
    const float* Pv = F + OF_Pq + 2 * 1440;
    const float* cv = F + OF_cq + 2 * ND;
    float p0 = 0.f, p1 = 0.f, p2 = 0.f, cc = 0.f;
    for (int d = lane; d < ND; d += 64) {
      float q = qrow[d];
      p0 += Pv[0 * ND + d] * q;
      p1 += Pv[1 * ND + d] * q;
      if (O == 3) p2 += Pv[2 * ND + d] * q;
      cc += cv[d] * q;
    }
    p0 = wave_sum(p0); p1 = wave_sum(p1); p2 = wave_sum(p2); cc = wave_sum(cc);
    if (lane == 0) {
      F[OF_Q2 + part * 1440 + 0 * ND + cc0] = p0;
      F[OF_Q2 + part * 1440 + 1 * ND + cc0] = p1;
      F[OF_Q2 + part * 1440 + 2 * ND + cc0] = (O == 3) ? p2 : 0.f;
      F[OF_dq + part * ND + cc0] = cc + c.qb[part * ND + cc0];
    }
  } else if (gid < 3 * ND + 16) {
    int s = gid - 3 * ND;
    const float* Pq = F + OF_Pq;
    const float* Pk = F + OF_Pq + 1440;
    const float* cq = F + OF_cq;
    const float* ck = F + OF_cq + ND;
    float acc = 0.f;
    if (s < 9) {
      int o = s / 3, op = s % 3;
      bool ok = (o < O) && (op < O);
      if (ok) for (int q = lane; q < ND; q += 64) acc += Pq[o * ND + q] * Pk[op * ND + q];
      acc = wave_sum(acc);
      if (lane == 0) F[OF_S + s] = ok ? acc : 0.f;
    } else if (s < 12) {
      int o = s - 9; bool ok = o < O;
      if (ok) for (int q = lane; q < ND; q += 64) acc += Pq[o * ND + q] * ck[q];
      acc = wave_sum(acc);
      if (lane == 0) F[OF_u + o] = ok ? acc : 0.f;
    } else if (s < 15) {
      int o = s - 12; bool ok = o < O;
      if (ok) for (int q = lane; q < ND; q += 64) acc += cq[q] * Pk[o * ND + q];
      acc = wave_sum(acc);
      if (lane == 0) F[OF_r + o] = ok ? acc : 0.f;
    } else {
      for (int q = lane; q < ND; q += 64) acc += cq[q] * ck[q];
      acc = wave_sum(acc);
      if (lane == 0) F[OF_w] = acc;
    }
  }
}

__global__ __launch_bounds__(256) void k_fold3B(FoldCfg A, FoldCfg Bc)
{
  FoldCfg c = (blockIdx.y == 0) ? A : Bc;
  int O = c.O;
  float* F = c.F;
  int s = blockIdx.x * 4 + (threadIdx.x >> 6);
  int lane = threadIdx.x & 63;
  if (s >= 16) return;
  const float* Q2 = F + OF_Q2;
  const float* K2 = F + OF_Q2 + 1440;
  const float* dq = F + OF_dq;
  const float* dk = F + OF_dq + ND;
  float acc = 0.f;
  if (s < 9) {
    int o = s / 3, op = s % 3;
    bool ok = (o < O) && (op < O);
    if (ok) for (int q = lane; q < ND; q += 64) acc += Q2[o * ND + q] * K2[op * ND + q];
    acc = wave_sum(acc);
    if (lane == 0) F[OF_S + 16 + s] = ok ? acc : 0.f;
  } else if (s < 12) {
    int o = s - 9; bool ok = o < O;
    if (ok) for (int q = lane; q < ND; q += 64) acc += Q2[o * ND + q] * dk[q];
    acc = wave_sum(acc);
    if (lane == 0) F[OF_u + 16 + o] = ok ? acc : 0.f;
  } else if (s < 15) {
    int o = s - 12; bool ok = o < O;
    if (ok) for (int q = lane; q < ND; q += 64) acc += dq[q] * K2[o * ND + q];
    acc = wave_sum(acc);
    if (lane == 0) F[OF_r + 16 + o] = ok ? acc : 0.f;
  } else {
    for (int q = lane; q < ND; q += 64) acc += dq[q] * dk[q];
    acc = wave_sum(acc);
    if (lane == 0) F[OF_w + 16] = acc;
  }
}

__global__ void k_type(const float* __restrict__ tl, const float* __restrict__ key_mask,
                       float* __restrict__ km2)
{
  int i = blockIdx.x * blockDim.x + threadIdx.x;
  if (i >= NB * NM) return;
  const float* p = tl + (size_t)i * NNV * 3;
  float l0 = p[0], l1 = p[1], l2 = p[2];
  int arg = 0;
  float best = l0;
  if (l1 > best) { best = l1; arg = 1; }
  if (l2 > best) { best = l2; arg = 2; }
  km2[i] = (key_mask[i] != 0.f && arg == 1) ? 1.f : 0.f;
}

__global__ void k_multi(const float* __restrict__ a, const float* __restrict__ bb,
                        const float* __restrict__ bc, float* __restrict__ out)
{
  int i = blockIdx.x * blockDim.x + threadIdx.x;
  if (i >= NB * NM * NM * 2) return;
  int c = i & 1;
  int t = i >> 1;
  int n = t % NM; t /= NM;
  int m = t % NM;
  int b = t / NM;
  out[i] = a[((size_t)b * NM + m) * 2 + c] + bb[((size_t)b * NM + n) * 2 + c] + bc[c];
}

extern "C" void kernel_launch(void* const* d_in, const int* in_sizes, int n_in,
                              void* d_out, int out_size, void* d_ws, size_t ws_size,
                              hipStream_t stream)
{
  const float* key        = (const float*)d_in[0];
  const float* value      = (const float*)d_in[1];
  const float* key_mask   = (const float*)d_in[2];
  const float* value_mask = (const float*)d_in[3];
  const float* w_kt = (const float*)d_in[4];  const float* b_kt = (const float*)d_in[5];
  const float* w_vt = (const float*)d_in[6];  const float* b_vt = (const float*)d_in[7];
  const float* w_km = (const float*)d_in[8];  const float* b_km = (const float*)d_in[9];
  const float* w_vm = (const float*)d_in[10]; const float* b_vm = (const float*)d_in[11];
  const float* w_ks = (const float*)d_in[12]; const float* b_ks = (const float*)d_in[13];
  const float* w_vs = (const float*)d_in[14]; const float* b_vs = (const float*)d_in[15];
  const float* bt_W = (const float*)d_in[16]; const float* bt_lw = (const float*)d_in[17];
  const float* bt_lb = (const float*)d_in[18];
  const float* bi_W = (const float*)d_in[19]; const float* bi_lw = (const float*)d_in[20];
  const float* bi_lb = (const float*)d_in[21];
  const float* w_ffnt = (const float*)d_in[22]; const float* b_ffnt = (const float*)d_in[23];
  const float* w_ffn  = (const float*)d_in[24]; const float* b_ffn  = (const float*)d_in[25];
  const float* qkvt_w = (const float*)d_in[26]; const float* qkvt_b = (const float*)d_in[27];
  const float* qkv_w  = (const float*)d_in[28]; const float* qkv_b  = (const float*)d_in[29];
  const float* w_cls  = (const float*)d_in[30]; const float* b_cls  = (const float*)d_in[31];

  float* ws = (float*)d_ws;
  size_t off = 0;
  auto alloc = [&](size_t nfloat) { float* p = ws + off; off += (nfloat + 3) & ~(size_t)3; return p; };

  // fp32 projections (die after sproj6; tmp planes alias this region afterwards)
  float* kt_t = alloc((size_t)NB * NM * ND);     // 983040
  float* vt_t = alloc((size_t)NB * NNV * ND);    // 998400
  float* kt_s = alloc((size_t)NB * NM * ND);     // 983040
  float* vt_s = alloc((size_t)NB * NM * ND);     // 983040  (total 3,947,520)
  float* kmf  = alloc((size_t)NB * NM * ND);
  float* vmf  = alloc((size_t)NB * NM * ND);
  float* linK_t = alloc((size_t)NB * NM * 3);
  float* linV_t = alloc((size_t)NB * NNV * 3);
  float* linK_s = alloc((size_t)NB * NM * 2);
  float* linV_s = alloc((size_t)NB * NM * 2);
  float* fold_t = alloc(FOLD_SZ);
  float* fold_s = alloc(FOLD_SZ);
  float* km2 = alloc((size_t)NB * NM);
  float* a2  = alloc((size_t)NB * NM * 2);
  float* b2  = alloc((size_t)NB * NM * 2);
  // u16 planes (alloc sizes in float units = n_u16/2)
  u16* WtH = (u16*)alloc((size_t)5 * ND * ND / 2);
  u16* WtL = (u16*)alloc((size_t)5 * ND * ND / 2);
  u16* keyH_t = (u16*)alloc((size_t)NB * NM * ND / 2);
  u16* keyL_t = (u16*)alloc((size_t)NB * NM * ND / 2);
  u16* keyH_s = (u16*)alloc((size_t)NB * NM * ND / 2);
  u16* keyL_s = (u16*)alloc((size_t)NB * NM * ND / 2);
  u16* valH_t = (u16*)alloc((size_t)NB * NNV * ND / 2);
  u16* valL_t = (u16*)alloc((size_t)NB * NNV * ND / 2);
  u16* valH_s = (u16*)alloc((size_t)NB * NM * ND / 2);
  u16* valL_s = (u16*)alloc((size_t)NB * NM * ND / 2);
  (void)ws_size; (void)in_sizes; (void)n_in; (void)out_size;

  // tmp planes alias the dead kt_t..vt_s region (needed: 2*1,474,560 floats <= 3,947,520)
  u16* tmpH = (u16*)kt_t;
  u16* tmpL = (u16*)(kt_t + 1474560);

  float* out_type   = (float*)d_out;
  float* out_multi  = out_type + (size_t)NB * NM * NNV * 3;
  float* out_single = out_multi + (size_t)NB * NM * NM * 2;

  dim3 blk(256);

  // 1. W^T planes for the 5 biaffine matrices
  k_cvtT<<<dim3(15, 15, 5), blk, 0, stream>>>(bt_W, bi_W, WtH, WtL);

  // 2. all 6 big projections (on-fly split, plane epilogues for c0..c3)
  Proj6 P;
  P.c[0] = { key,   w_kt, b_kt, kt_t, keyH_t, keyL_t, NB * NM,  0, NM,  NM * NH };
  P.c[1] = { value, w_vt, b_vt, vt_t, valH_t, valL_t, NB * NNV, 0, NNV, NNV * NH };
  P.c[2] = { key,   w_ks, b_ks, kt_s, keyH_s, keyL_s, NB * NM,  0, NM,  NM * NH };
  P.c[3] = { value, w_vs, b_vs, vt_s, valH_s, valL_s, NB * NM,  1, NM,  NNV * NH };
  P.c[4] = { key,   w_km, b_km, kmf,  nullptr, nullptr, NB * NM, 0, NM, NM * NH };
  P.c[5] = { value, w_vm, b_vm, vmf,  nullptr, nullptr, NB * NM, 1, NM, NNV * NH };
  k_projM<<<dim3(193 * 10), blk, 0, stream>>>(P, NH);

  // 3-5. folds
  FoldCfg ft = { w_ffnt, b_ffnt, qkvt_w, qkvt_b, fold_t, 3 };
  FoldCfg fs = { w_ffn,  b_ffn,  qkv_w,  qkv_b,  fold_s, 2 };
  k_fold1B<<<dim3(360, 2), blk, 0, stream>>>(ft, fs);
  k_fold2B<<<dim3(364, 2), blk, 0, stream>>>(ft, fs);
  k_fold3B<<<dim3(4, 2), blk, 0, stream>>>(ft, fs);

  // 6. all small matvecs
  SpCfg s0 = { kt_t, bt_lw, linK_t, NB * NM,  3, 2 * ND, 0 };
  SpCfg s1 = { vt_t, bt_lw, linV_t, NB * NNV, 3, 2 * ND, ND };
  SpCfg s2 = { kt_s, bi_lw, linK_s, NB * NM,  2, 2 * ND, 0 };
  SpCfg s3 = { vt_s, bi_lw, linV_s, NB * NM,  2, 2 * ND, ND };
  SpCfg s4 = { kmf,  w_cls, a2,     NB * NM,  2, 2 * ND, 0 };
  SpCfg s5 = { vmf,  w_cls, b2,     NB * NM,  2, 2 * ND, ND };
  k_sproj6<<<dim3((NB * NNV * 3 + 3) / 4, 6), blk, 0, stream>>>(s0, s1, s2, s3, s4, s5);

  // 7. multi logits
  k_multi<<<dim3((NB * NM * NM * 2 + 255) / 256), blk, 0, stream>>>(a2, b2, b_cls, out_multi);

  // 8. type path: all 5 rounds in one kernel
  k_mega<3, NNV><<<dim3(NB), dim3(1024), 0, stream>>>(
      WtH, WtL, tmpH, tmpL, keyH_t, keyL_t, valH_t, valL_t,
      key_mask, value_mask, 0, NNV,
      fold_t, bt_lw, bt_lb, linK_t, linV_t, out_type);

  // 9. type decision -> km2
  k_type<<<dim3(8), blk, 0, stream>>>(out_type, key_mask, km2);

  // 10. single path: all 5 rounds in one kernel
  k_mega<2, NM><<<dim3(NB), dim3(1024), 0, stream>>>(
      WtH + (size_t)3 * ND * ND, WtL + (size_t)3 * ND * ND,
      tmpH, tmpL, keyH_s, keyL_s, valH_s, valL_s,
      km2, value_mask, 1, NNV,
      fold_s, bi_lw, bi_lb, linK_s, linV_s, out_single);
}

// Round 9
// 3430.928 us; speedup vs baseline: 1.2153x; 1.2153x over previous
//
#include <hip/hip_runtime.h>
#include <hip/hip_cooperative_groups.h>
#include <math.h>

namespace cg = cooperative_groups;

// ---------------- problem constants ----------------
constexpr int NB = 32;    // B
constexpr int NM = 64;    // M
constexpr int NNV = 65;   // NV
constexpr int NH = 960;   // H
constexpr int ND = 480;   // D
constexpr float ATT_SCALE = 0.045643546458763842f;  // D^-0.5

constexpr int OF_Pq = 0;
constexpr int OF_cq = 4320;
constexpr int OF_Q2 = 5760;
constexpr int OF_V2 = OF_Q2 + 2*1440;
constexpr int OF_dq = 10080;
constexpr int OF_dv = OF_dq + 2*480;
constexpr int OF_S  = 11520;
constexpr int OF_u  = 11529;
constexpr int OF_r  = 11532;
constexpr int OF_w  = 11535;
constexpr int FOLD_SZ = 11552;

typedef unsigned short u16;
typedef float f32x4 __attribute__((ext_vector_type(4)));
typedef short s16x8 __attribute__((ext_vector_type(8)));

__device__ __forceinline__ float wave_sum(float v) {
#pragma unroll
  for (int d = 32; d; d >>= 1) v += __shfl_xor(v, d);
  return v;
}

__device__ __forceinline__ void split_bf16(float x, short& hi, short& lo) {
  union { float f; unsigned u; } a; a.f = x;
  unsigned uh = a.u + 0x7fffu + ((a.u >> 16) & 1u);
  hi = (short)(uh >> 16);
  union { unsigned u; float f; } b; b.u = ((unsigned)(unsigned short)hi) << 16;
  union { float f; unsigned u; } c; c.f = x - b.f;
  unsigned ul = c.u + 0x7fffu + ((c.u >> 16) & 1u);
  lo = (short)(ul >> 16);
}

__device__ __forceinline__ float join_bf16(u16 h, u16 l) {
  union { unsigned u; float f; } a, b;
  a.u = ((unsigned)h) << 16; b.u = ((unsigned)l) << 16;
  return a.f + b.f;
}

// transpose-convert: dst[z][n][k] = split(src[z][k][n]) for 5 planes (bt_W 0..2, bi_W 0..1)
__global__ __launch_bounds__(256) void k_cvtT(
    const float* __restrict__ btW, const float* __restrict__ biW,
    u16* __restrict__ wtHi, u16* __restrict__ wtLo)
{
  __shared__ float s[32][33];
  const int z = blockIdx.z;
  const float* src = (z < 3) ? (btW + (size_t)z * ND * ND) : (biW + (size_t)(z - 3) * ND * ND);
  u16* dh = wtHi + (size_t)z * ND * ND;
  u16* dl = wtLo + (size_t)z * ND * ND;
  const int k0 = blockIdx.y * 32, n0 = blockIdx.x * 32;
  const int tx = threadIdx.x & 31, ty = threadIdx.x >> 5;
#pragma unroll
  for (int q = 0; q < 4; ++q)
    s[ty + q * 8][tx] = src[(size_t)(k0 + ty + q * 8) * ND + n0 + tx];
  __syncthreads();
#pragma unroll
  for (int q = 0; q < 4; ++q) {
    float v = s[tx][ty + q * 8];
    short h, l; split_bf16(v, h, l);
    size_t di = (size_t)(n0 + ty + q * 8) * ND + k0 + tx;
    dh[di] = (u16)h; dl[di] = (u16)l;
  }
}

// ---------------- MFMA projection GEMM (on-fly split) + plane epilogue ----------------
struct ProjCfg {
  const float* X; const float* W; const float* bias; float* C;
  u16* pH; u16* pL;
  int R; int x0; int rpb; int xbs;
};
struct Proj6 { ProjCfg c[6]; };

constexpr int KP = 40;

__global__ __launch_bounds__(256) void k_projM(Proj6 P, int K)
{
  __shared__ u16 As_hi[64][KP], As_lo[64][KP];
  __shared__ u16 Bs_hi[48][KP], Bs_lo[48][KP];
  int p = blockIdx.x, total = gridDim.x;
  int q = total >> 3, r = total & 7;
  int xk = p & 7, idx = p >> 3;
  int lgc = (xk < r) ? (xk * (q + 1) + idx) : (r * (q + 1) + (xk - r) * q + idx);
  int mp = lgc / 10, nx = lgc - mp * 10;
  ProjCfg cfg; int my;
  if      (mp < 32)  { cfg = P.c[0]; my = mp; }
  else if (mp < 65)  { cfg = P.c[1]; my = mp - 32; }
  else if (mp < 97)  { cfg = P.c[2]; my = mp - 65; }
  else if (mp < 129) { cfg = P.c[3]; my = mp - 97; }
  else if (mp < 161) { cfg = P.c[4]; my = mp - 129; }
  else               { cfg = P.c[5]; my = mp - 161; }
  const int m0 = my * 64, n0 = nx * 48;
  const int tid = threadIdx.x;
  const int l6 = tid & 63, w = tid >> 6;
  const int lr = tid >> 2, kc = (tid & 3) * 8;
  const float* Arow = nullptr;
  {
    int rr = m0 + lr;
    if (rr < cfg.R) {
      int b = rr / cfg.rpb, r2 = rr - b * cfg.rpb;
      Arow = cfg.X + (size_t)b * cfg.xbs + (size_t)(cfg.x0 + r2) * K;
    }
  }
  const float* Brow = (lr < 48) ? (cfg.W + (size_t)(n0 + lr) * K) : nullptr;
  const int fr = l6 & 15, fk = (l6 >> 4) * 8;
  f32x4 acc0 = {0.f, 0.f, 0.f, 0.f}, acc1 = acc0, acc2 = acc0;
  for (int k0 = 0; k0 < K; k0 += 32) {
    float xs[8] = {0.f, 0.f, 0.f, 0.f, 0.f, 0.f, 0.f, 0.f};
    if (Arow) {
      float4 a0 = *(const float4*)(Arow + k0 + kc);
      float4 a1 = *(const float4*)(Arow + k0 + kc + 4);
      xs[0] = a0.x; xs[1] = a0.y; xs[2] = a0.z; xs[3] = a0.w;
      xs[4] = a1.x; xs[5] = a1.y; xs[6] = a1.z; xs[7] = a1.w;
    }
    s16x8 vh, vl;
#pragma unroll
    for (int e = 0; e < 8; ++e) { short h, lo2; split_bf16(xs[e], h, lo2); vh[e] = h; vl[e] = lo2; }
    *(s16x8*)&As_hi[lr][kc] = vh;
    *(s16x8*)&As_lo[lr][kc] = vl;
    if (Brow) {
      float4 b0 = *(const float4*)(Brow + k0 + kc);
      float4 b1 = *(const float4*)(Brow + k0 + kc + 4);
      float ys[8] = {b0.x, b0.y, b0.z, b0.w, b1.x, b1.y, b1.z, b1.w};
      s16x8 wh, wl;
#pragma unroll
      for (int e = 0; e < 8; ++e) { short h, lo2; split_bf16(ys[e], h, lo2); wh[e] = h; wl[e] = lo2; }
      *(s16x8*)&Bs_hi[lr][kc] = wh;
      *(s16x8*)&Bs_lo[lr][kc] = wl;
    }
    __syncthreads();
    s16x8 ah = *(const s16x8*)&As_hi[16 * w + fr][fk];
    s16x8 al = *(const s16x8*)&As_lo[16 * w + fr][fk];
    {
      s16x8 bh = *(const s16x8*)&Bs_hi[fr][fk];
      s16x8 bl = *(const s16x8*)&Bs_lo[fr][fk];
      acc0 = __builtin_amdgcn_mfma_f32_16x16x32_bf16(ah, bh, acc0, 0, 0, 0);
      acc0 = __builtin_amdgcn_mfma_f32_16x16x32_bf16(ah, bl, acc0, 0, 0, 0);
      acc0 = __builtin_amdgcn_mfma_f32_16x16x32_bf16(al, bh, acc0, 0, 0, 0);
    }
    {
      s16x8 bh = *(const s16x8*)&Bs_hi[16 + fr][fk];
      s16x8 bl = *(const s16x8*)&Bs_lo[16 + fr][fk];
      acc1 = __builtin_amdgcn_mfma_f32_16x16x32_bf16(ah, bh, acc1, 0, 0, 0);
      acc1 = __builtin_amdgcn_mfma_f32_16x16x32_bf16(ah, bl, acc1, 0, 0, 0);
      acc1 = __builtin_amdgcn_mfma_f32_16x16x32_bf16(al, bh, acc1, 0, 0, 0);
    }
    {
      s16x8 bh = *(const s16x8*)&Bs_hi[32 + fr][fk];
      s16x8 bl = *(const s16x8*)&Bs_lo[32 + fr][fk];
      acc2 = __builtin_amdgcn_mfma_f32_16x16x32_bf16(ah, bh, acc2, 0, 0, 0);
      acc2 = __builtin_amdgcn_mfma_f32_16x16x32_bf16(ah, bl, acc2, 0, 0, 0);
      acc2 = __builtin_amdgcn_mfma_f32_16x16x32_bf16(al, bh, acc2, 0, 0, 0);
    }
    __syncthreads();
  }
#pragma unroll
  for (int c = 0; c < 3; ++c) {
    f32x4 av = (c == 0) ? acc0 : (c == 1) ? acc1 : acc2;
    int n = n0 + 16 * c + fr;
    float bv = cfg.bias[n];
#pragma unroll
    for (int g = 0; g < 4; ++g) {
      int rr = m0 + 16 * w + (l6 >> 4) * 4 + g;
      if (rr < cfg.R) {
        float v = av[g] + bv;
        size_t di = (size_t)rr * ND + n;
        cfg.C[di] = v;
        if (cfg.pH) {
          short h, lo2; split_bf16(v, h, lo2);
          cfg.pH[di] = (u16)h; cfg.pL[di] = (u16)lo2;
        }
      }
    }
  }
}

// ================= shared phase device code =================
struct PathP {
  const u16* WtH; const u16* WtL;     // [O][480][480] (n,k)
  u16* keyH; u16* keyL;               // [NB][64][480]
  u16* valH; u16* valL;               // [NB][NVX][480]
  const float* kmp; const float* vmp; int vmOff; int vmStride;
  const float* F; const float* lw; const float* lb;
  float* linK; float* linV;
  float* outp;
  int O; int NVX; int NT;
};
struct CoopP {
  PathP pa; PathP pb;
  u16* tmpH; u16* tmpL;               // [NB][O][64][480]
  float* Lg; float* Yg;               // [NB][64][NVX][3]
  const float* key_mask; float* km2;
};

__device__ __forceinline__ void phase_G(
    const CoopP& P, const PathP& p, int wid, int nw, int fr, int fko, int rquad)
{
  const int O = p.O;
  const int GJ = NB * O * 30;
  for (int t = wid; t < GJ; t += nw) {
    int b = t / (O * 30); int rem = t - b * (O * 30);
    int o = rem / 30, nt = rem - o * 30;
    const u16* kH = p.keyH + (size_t)b * NM * ND;
    const u16* kL = p.keyL + (size_t)b * NM * ND;
    const u16* bHp = p.WtH + ((size_t)o * ND + nt * 16 + fr) * ND + fko;
    const u16* bLp = p.WtL + ((size_t)o * ND + nt * 16 + fr) * ND + fko;
    f32x4 z4 = {0.f, 0.f, 0.f, 0.f};
    f32x4 am[4] = {z4, z4, z4, z4};
    for (int k0 = 0; k0 < ND; k0 += 32) {
      s16x8 bh = *(const s16x8*)(bHp + k0);
      s16x8 bl = *(const s16x8*)(bLp + k0);
#pragma unroll
      for (int mt = 0; mt < 4; ++mt) {
        s16x8 ah = *(const s16x8*)(kH + (size_t)(mt * 16 + fr) * ND + fko + k0);
        s16x8 al = *(const s16x8*)(kL + (size_t)(mt * 16 + fr) * ND + fko + k0);
        am[mt] = __builtin_amdgcn_mfma_f32_16x16x32_bf16(ah, bh, am[mt], 0, 0, 0);
        am[mt] = __builtin_amdgcn_mfma_f32_16x16x32_bf16(ah, bl, am[mt], 0, 0, 0);
        am[mt] = __builtin_amdgcn_mfma_f32_16x16x32_bf16(al, bh, am[mt], 0, 0, 0);
      }
    }
    int n = nt * 16 + fr;
    u16* tH = P.tmpH + ((size_t)b * O + o) * NM * ND;
    u16* tL = P.tmpL + ((size_t)b * O + o) * NM * ND;
#pragma unroll
    for (int mt = 0; mt < 4; ++mt)
#pragma unroll
      for (int g = 0; g < 4; ++g) {
        int m = mt * 16 + rquad + g;
        short h, lo2; split_bf16(am[mt][g], h, lo2);
        size_t di = (size_t)m * ND + n;
        tH[di] = (u16)h; tL[di] = (u16)lo2;
      }
  }
}

__device__ __forceinline__ void phase_BIL(
    const CoopP& P, const PathP& p, bool fin, int wid, int nw, int fr, int fko, int rquad)
{
  const int O = p.O, NVX = p.NVX, NT = p.NT;
  const s16x8 zf = {0, 0, 0, 0, 0, 0, 0, 0};
  const int BJ = NB * O * NT;
  for (int t = wid; t < BJ; t += nw) {
    int b = t / (O * NT); int rem = t - b * (O * NT);
    int o = rem / NT, nt = rem - o * NT;
    int n = nt * 16 + fr;
    bool nok = n < NVX;
    const u16* vH = p.valH + ((size_t)b * NVX + (nok ? n : 0)) * ND + fko;
    const u16* vL = p.valL + ((size_t)b * NVX + (nok ? n : 0)) * ND + fko;
    const u16* tH = P.tmpH + ((size_t)b * O + o) * NM * ND;
    const u16* tL = P.tmpL + ((size_t)b * O + o) * NM * ND;
    f32x4 z4 = {0.f, 0.f, 0.f, 0.f};
    f32x4 am[4] = {z4, z4, z4, z4};
    for (int k0 = 0; k0 < ND; k0 += 32) {
      s16x8 bh = nok ? *(const s16x8*)(vH + k0) : zf;
      s16x8 bl = nok ? *(const s16x8*)(vL + k0) : zf;
#pragma unroll
      for (int mt = 0; mt < 4; ++mt) {
        s16x8 ah = *(const s16x8*)(tH + (size_t)(mt * 16 + fr) * ND + fko + k0);
        s16x8 al = *(const s16x8*)(tL + (size_t)(mt * 16 + fr) * ND + fko + k0);
        am[mt] = __builtin_amdgcn_mfma_f32_16x16x32_bf16(ah, bh, am[mt], 0, 0, 0);
        am[mt] = __builtin_amdgcn_mfma_f32_16x16x32_bf16(ah, bl, am[mt], 0, 0, 0);
        am[mt] = __builtin_amdgcn_mfma_f32_16x16x32_bf16(al, bh, am[mt], 0, 0, 0);
      }
    }
    if (nok) {
      float lbo = p.lb[o];
      float vmn = fin ? p.vmp[b * p.vmStride + p.vmOff + n] : 0.f;
#pragma unroll
      for (int mt = 0; mt < 4; ++mt)
#pragma unroll
        for (int g = 0; g < 4; ++g) {
          int m = mt * 16 + rquad + g;
          float v = am[mt][g] + p.linK[(size_t)(b * NM + m) * O + o]
                              + p.linV[(size_t)(b * NVX + n) * O + o] + lbo;
          if (!fin)
            P.Lg[(((size_t)b * NM + m) * NVX + n) * 3 + o] = v;
          else
            p.outp[(((size_t)b * NM + m) * NVX + n) * O + o] =
                v * p.kmp[b * NM + m] * vmn;
        }
    }
  }
}

__device__ __forceinline__ void phase_att0(
    const CoopP& P, const PathP& p, int gtid, int gsz)
{
  const int O = p.O, NVX = p.NVX;
  const float* F = p.F;
  const int AJ = NB * NM * NVX;
  for (int t = gtid; t < AJ; t += gsz) {
    int bm = t / NVX, i = t - bm * NVX;
    int b = bm >> 6;
    const float* Lr = P.Lg + (size_t)bm * NVX * 3;
    float Li0 = Lr[i * 3], Li1 = Lr[i * 3 + 1], Li2 = (O == 3) ? Lr[i * 3 + 2] : 0.f;
    float st0 = Li0 * F[OF_S + 0] + Li1 * F[OF_S + 3] + Li2 * F[OF_S + 6];
    float st1 = Li0 * F[OF_S + 1] + Li1 * F[OF_S + 4] + Li2 * F[OF_S + 7];
    float st2 = Li0 * F[OF_S + 2] + Li1 * F[OF_S + 5] + Li2 * F[OF_S + 8];
    float hi = Li0 * F[OF_u] + Li1 * F[OF_u + 1] + Li2 * F[OF_u + 2];
    float r0 = F[OF_r], r1 = F[OF_r + 1], r2 = F[OF_r + 2], wc = F[OF_w];
    bool rowz = (p.kmp[bm] == 0.f) || (p.vmp[b * p.vmStride + p.vmOff + i] == 0.f);
    float mx = -3.0e38f, sum = 0.f, y0 = 0.f, y1 = 0.f, y2 = 0.f;
    for (int j = 0; j < NVX; ++j) {
      float t0 = Lr[j * 3], t1 = Lr[j * 3 + 1], t2 = (O == 3) ? Lr[j * 3 + 2] : 0.f;
      float s = st0 * t0 + st1 * t1 + st2 * t2 + hi + (t0 * r0 + t1 * r1 + t2 * r2) + wc;
      s = (rowz || p.vmp[b * p.vmStride + p.vmOff + j] == 0.f) ? -10000.f : ATT_SCALE * s;
      float nm = fmaxf(mx, s);
      float pp = __expf(s - nm), cc = __expf(mx - nm);
      sum = sum * cc + pp; y0 = y0 * cc + pp * t0; y1 = y1 * cc + pp * t1; y2 = y2 * cc + pp * t2;
      mx = nm;
    }
    float inv = 1.f / sum;
    float* Yw = P.Yg + ((size_t)bm * NVX + i) * 3;
    Yw[0] = y0 * inv; Yw[1] = y1 * inv;
    if (O == 3) Yw[2] = y2 * inv;
  }
}

__device__ __forceinline__ void phase_att1(
    const CoopP& P, const PathP& p, int gtid, int gsz)
{
  const int O = p.O, NVX = p.NVX;
  const float* F = p.F + 16;
  const int AJ = NB * NVX * NM;
  for (int t = gtid; t < AJ; t += gsz) {
    int bn = t >> 6, i = t & 63;
    int b = bn / NVX, n = bn - b * NVX;
    const float* Yb = P.Yg + ((size_t)b * NM * NVX + n) * 3;
    float Yi0 = Yb[(size_t)i * NVX * 3], Yi1 = Yb[(size_t)i * NVX * 3 + 1];
    float Yi2 = (O == 3) ? Yb[(size_t)i * NVX * 3 + 2] : 0.f;
    float st0 = Yi0 * F[OF_S + 0] + Yi1 * F[OF_S + 3] + Yi2 * F[OF_S + 6];
    float st1 = Yi0 * F[OF_S + 1] + Yi1 * F[OF_S + 4] + Yi2 * F[OF_S + 7];
    float st2 = Yi0 * F[OF_S + 2] + Yi1 * F[OF_S + 5] + Yi2 * F[OF_S + 8];
    float hi = Yi0 * F[OF_u] + Yi1 * F[OF_u + 1] + Yi2 * F[OF_u + 2];
    float r0 = F[OF_r], r1 = F[OF_r + 1], r2 = F[OF_r + 2], wc = F[OF_w];
    bool rowz = (p.vmp[b * p.vmStride + p.vmOff + n] == 0.f) || (p.kmp[b * NM + i] == 0.f);
    float mx = -3.0e38f, sum = 0.f, y0 = 0.f, y1 = 0.f, y2 = 0.f;
    for (int j = 0; j < NM; ++j) {
      const float* Yj = Yb + (size_t)j * NVX * 3;
      float t0 = Yj[0], t1 = Yj[1], t2 = (O == 3) ? Yj[2] : 0.f;
      float s = st0 * t0 + st1 * t1 + st2 * t2 + hi + (t0 * r0 + t1 * r1 + t2 * r2) + wc;
      s = (rowz || p.kmp[b * NM + j] == 0.f) ? -10000.f : ATT_SCALE * s;
      float nm = fmaxf(mx, s);
      float pp = __expf(s - nm), cc = __expf(mx - nm);
      sum = sum * cc + pp; y0 = y0 * cc + pp * t0; y1 = y1 * cc + pp * t1; y2 = y2 * cc + pp * t2;
      mx = nm;
    }
    float inv = 1.f / sum;
    float* Lw = P.Lg + (((size_t)b * NM + i) * NVX + n) * 3;
    Lw[0] = y0 * inv; Lw[1] = y1 * inv;
    if (O == 3) Lw[2] = y2 * inv;
  }
}

__device__ __forceinline__ void phase_upd(
    const CoopP& P, const PathP& p, int gtid, int gsz, int l)
{
  const int O = p.O, NVX = p.NVX;
  const float* V2 = p.F + OF_V2;
  const float* dvp = p.F + OF_dv;
  const int UJ = NB * (NVX + NM) * 128;
  for (int t = gtid; t < UJ; t += gsz) {
    int row = t >> 7, dg = t & 127;
    bool isval = row < NB * NVX;
    int b, idx;
    if (isval) { b = row / NVX; idx = row - b * NVX; }
    else { int r2 = row - NB * NVX; b = r2 >> 6; idx = r2 & 63; }
    bool act = dg < 120;
    int d0 = dg * 4;
    float p0 = 0.f, p1 = 0.f, p2 = 0.f;
    if (act) {
      float v0[4], v1[4], v2[4], dl4[4];
#pragma unroll
      for (int e = 0; e < 4; ++e) {
        v0[e] = V2[d0 + e]; v1[e] = V2[ND + d0 + e];
        v2[e] = (O == 3) ? V2[2 * ND + d0 + e] : 0.f;
        dl4[e] = dvp[d0 + e];
      }
      float mx[4] = {-3.0e38f, -3.0e38f, -3.0e38f, -3.0e38f};
      if (isval) {
        const float* Yc = P.Lg + ((size_t)b * NM * NVX + idx) * 3;
        for (int j = 0; j < NM; ++j) {
          const float* Yj = Yc + (size_t)j * NVX * 3;
          float y0 = Yj[0], y1 = Yj[1], y2 = (O == 3) ? Yj[2] : 0.f;
#pragma unroll
          for (int e = 0; e < 4; ++e)
            mx[e] = fmaxf(mx[e], y0 * v0[e] + y1 * v1[e] + y2 * v2[e]);
        }
      } else {
        const float* Yc = P.Lg + ((size_t)b * NM + idx) * NVX * 3;
        for (int j = 0; j < NVX; ++j) {
          float y0 = Yc[j * 3], y1 = Yc[j * 3 + 1], y2 = (O == 3) ? Yc[j * 3 + 2] : 0.f;
#pragma unroll
          for (int e = 0; e < 4; ++e)
            mx[e] = fmaxf(mx[e], y0 * v0[e] + y1 * v1[e] + y2 * v2[e]);
        }
      }
      u16* pH = isval ? p.valH : p.keyH;
      u16* pL = isval ? p.valL : p.keyL;
      size_t rb = isval ? ((size_t)b * NVX + idx) * ND : ((size_t)b * NM + idx) * ND;
      int lwoff = isval ? ND : 0;
#pragma unroll
      for (int e = 0; e < 4; ++e) {
        float delta = mx[e] + dl4[e];
        size_t gi = rb + d0 + e;
        float nv = join_bf16(pH[gi], pL[gi]) + delta;
        short h, lo2; split_bf16(nv, h, lo2);
        pH[gi] = (u16)h; pL[gi] = (u16)lo2;
        p0 += delta * p.lw[lwoff + d0 + e];
        p1 += delta * p.lw[2 * ND + lwoff + d0 + e];
        if (O == 3) p2 += delta * p.lw[4 * ND + lwoff + d0 + e];
      }
    }
    p0 = wave_sum(p0); p1 = wave_sum(p1);
    if (O == 3) p2 = wave_sum(p2);
    if (l == 0) {
      float* lin = isval ? (p.linV + (size_t)(b * NVX + idx) * O)
                         : (p.linK + (size_t)(b * NM + idx) * O);
      atomicAdd(&lin[0], p0);
      atomicAdd(&lin[1], p1);
      if (O == 3) atomicAdd(&lin[2], p2);
    }
  }
}

__device__ __forceinline__ void phase_type(const CoopP& P, int gtid, int gsz)
{
  for (int i = gtid; i < NB * NM; i += gsz) {
    const float* q = P.pa.outp + (size_t)i * NNV * 3;
    float l0 = q[0], l1 = q[1], l2 = q[2];
    int arg = 0; float best = l0;
    if (l1 > best) { best = l1; arg = 1; }
    if (l2 > best) { arg = 2; }
    P.km2[i] = (P.key_mask[i] != 0.f && arg == 1) ? 1.f : 0.f;
  }
}

// ---- cooperative whole-pipeline kernel ----
__global__ __launch_bounds__(256, 2) void k_coop(CoopP P)
{
  cg::grid_group gg = cg::this_grid();
  const int gtid = blockIdx.x * 256 + threadIdx.x;
  const int gsz = gridDim.x * 256;
  const int wid = gtid >> 6, nw = gsz >> 6;
  const int l = threadIdx.x & 63;
  const int fr = l & 15, fko = (l >> 4) * 8, rquad = (l >> 4) * 4;
  for (int path = 0; path < 2; ++path) {
    PathP p = path ? P.pb : P.pa;
    for (int r = 0; r < 5; ++r) {
      phase_G(P, p, wid, nw, fr, fko, rquad);
      gg.sync();
      bool fin = (r == 4);
      phase_BIL(P, p, fin, wid, nw, fr, fko, rquad);
      gg.sync();
      if (fin) break;
      phase_att0(P, p, gtid, gsz);
      gg.sync();
      phase_att1(P, p, gtid, gsz);
      gg.sync();
      phase_upd(P, p, gtid, gsz, l);
      gg.sync();
    }
    if (path == 0) { phase_type(P, gtid, gsz); gg.sync(); }
  }
}

// ---- fallback: one phase per launch ----
__global__ __launch_bounds__(256) void k_phase(CoopP P, int path, int phase, int fin)
{
  const int gtid = blockIdx.x * 256 + threadIdx.x;
  const int gsz = gridDim.x * 256;
  const int wid = gtid >> 6, nw = gsz >> 6;
  const int l = threadIdx.x & 63;
  const int fr = l & 15, fko = (l >> 4) * 8, rquad = (l >> 4) * 4;
  PathP p = path ? P.pb : P.pa;
  if (phase == 0) phase_G(P, p, wid, nw, fr, fko, rquad);
  else if (phase == 1) phase_BIL(P, p, fin != 0, wid, nw, fr, fko, rquad);
  else if (phase == 2) phase_att0(P, p, gtid, gsz);
  else if (phase == 3) phase_att1(P, p, gtid, gsz);
  else if (phase == 4) phase_upd(P, p, gtid, gsz, l);
  else phase_type(P, gtid, gsz);
}

// batched small matvec: Out[r,o] = X[r,:]·W[o, wOff:wOff+480]
struct SpCfg { const float* X; const float* W; float* Out; int R; int O; int wStride; int wOff; };
__global__ __launch_bounds__(256) void k_sproj6(
    SpCfg s0, SpCfg s1, SpCfg s2, SpCfg s3, SpCfg s4, SpCfg s5)
{
  int z = blockIdx.y;
  SpCfg c = (z == 0) ? s0 : (z == 1) ? s1 : (z == 2) ? s2 : (z == 3) ? s3 : (z == 4) ? s4 : s5;
  int gid = blockIdx.x * 4 + (threadIdx.x >> 6);
  if (gid >= c.R * c.O) return;
  int lane = threadIdx.x & 63;
  int r = gid / c.O, o = gid - r * c.O;
  const float* x = c.X + (size_t)r * ND;
  const float* wp = c.W + (size_t)o * c.wStride + c.wOff;
  float acc = 0.f;
  for (int d = lane; d < ND; d += 64) acc += x[d] * wp[d];
  acc = wave_sum(acc);
  if (lane == 0) c.Out[gid] = acc;
}

// ---------------- folds ----------------
struct FoldCfg { const float* fw; const float* fb; const float* qw; const float* qb; float* F; int O; };

__global__ __launch_bounds__(256) void k_fold1B(FoldCfg A, FoldCfg Bc)
{
  FoldCfg c = (blockIdx.y == 0) ? A : Bc;
  int O = c.O;
  int gid = blockIdx.x * 4 + (threadIdx.x >> 6);
  int lane = threadIdx.x & 63;
  if (gid >= 3 * ND) return;
  int part = gid / ND, cc0 = gid - part * ND;
  const float* qrow = c.qw + (size_t)(part * ND + cc0) * ND;
  float p0 = 0.f, p1 = 0.f, p2 = 0.f, cc = 0.f;
  for (int d = lane; d < ND; d += 64) {
    float q = qrow[d];
    p0 += c.fw[d * O + 0] * q;
    p1 += c.fw[d * O + 1] * q;
    if (O == 3) p2 += c.fw[d * O + 2] * q;
    cc += c.fb[d] * q;
  }
  p0 = wave_sum(p0); p1 = wave_sum(p1); p2 = wave_sum(p2); cc = wave_sum(cc);
  if (lane == 0) {
    c.F[OF_Pq + part * 1440 + 0 * ND + cc0] = p0;
    c.F[OF_Pq + part * 1440 + 1 * ND + cc0] = p1;
    c.F[OF_Pq + part * 1440 + 2 * ND + cc0] = (O == 3) ? p2 : 0.f;
    c.F[OF_cq + part * ND + cc0] = cc + c.qb[part * ND + cc0];
  }
}

__global__ __launch_bounds__(256) void k_fold2B(FoldCfg A, FoldCfg Bc)
{
  FoldCfg c = (blockIdx.y == 0) ? A : Bc;
  int O = c.O;
  float* F = c.F;
  int gid = blockIdx.x * 4 + (threadIdx.x >> 6);
  int lane = threadIdx.x & 63;
  if (gid < 3 * ND) {
    int part = gid / ND, cc0 = gid - part * ND;
    const float* qrow = c.qw + (size_t)(part * ND + cc0) * ND;
    const float* Pv = F + OF_Pq + 2 * 1440;
    const float* cv = F + OF_cq + 2 * ND;
    float p0 = 0.f, p1 = 0.f, p2 = 0.f, cc = 0.f;
    for (int d = lane; d < ND; d += 64) {
      float q = qrow[d];
      p0 += Pv[0 * ND + d] * q;
      p1 += Pv[1 * ND + d] * q;
      if (O == 3) p2 += Pv[2 * ND + d] * q;
      cc += cv[d] * q;
    }
    p0 = wave_sum(p0); p1 = wave_sum(p1); p2 = wave_sum(p2); cc = wave_sum(cc);
    if (lane == 0) {
      F[OF_Q2 + part * 1440 + 0 * ND + cc0] = p0;
      F[OF_Q2 + part * 1440 + 1 * ND + cc0] = p1;
      F[OF_Q2 + part * 1440 + 2 * ND + cc0] = (O == 3) ? p2 : 0.f;
      F[OF_dq + part * ND + cc0] = cc + c.qb[part * ND + cc0];
    }
  } else if (gid < 3 * ND + 16) {
    int s = gid - 3 * ND;
    const float* Pq = F + OF_Pq;
    const float* Pk = F + OF_Pq + 1440;
    const float* cq = F + OF_cq;
    const float* ck = F + OF_cq + ND;
    float acc = 0.f;
    if (s < 9) {
      int o = s / 3, op = s % 3;
      bool ok = (o < O) && (op < O);
      if (ok) for (int q = lane; q < ND; q += 64) acc += Pq[o * ND + q] * Pk[op * ND + q];
      acc = wave_sum(acc);
      if (lane == 0) F[OF_S + s] = ok ? acc : 0.f;
    } else if (s < 12) {
      int o = s - 9; bool ok = o < O;
      if (ok) for (int q = lane; q < ND; q += 64) acc += Pq[o * ND + q] * ck[q];
      acc = wave_sum(acc);
      if (lane == 0) F[OF_u + o] = ok ? acc : 0.f;
    } else if (s < 15) {
      int o = s - 12; bool ok = o < O;
      if (ok) for (int q = lane; q < ND; q += 64) acc += cq[q] * Pk[o * ND + q];
      acc = wave_sum(acc);
      if (lane == 0) F[OF_r + o] = ok ? acc : 0.f;
    } else {
      for (int q = lane; q < ND; q += 64) acc += cq[q] * ck[q];
      acc = wave_sum(acc);
      if (lane == 0) F[OF_w] = acc;
    }
  }
}

__global__ __launch_bounds__(256) void k_fold3B(FoldCfg A, FoldCfg Bc)
{
  FoldCfg c = (blockIdx.y == 0) ? A : Bc;
  int O = c.O;
  float* F = c.F;
  int s = blockIdx.x * 4 + (threadIdx.x >> 6);
  int lane = threadIdx.x & 63;
  if (s >= 16) return;
  const float* Q2 = F + OF_Q2;
  const float* K2 = F + OF_Q2 + 1440;
  const float* dq = F + OF_dq;
  const float* dk = F + OF_dq + ND;
  float acc = 0.f;
  if (s < 9) {
    int o = s / 3, op = s % 3;
    bool ok = (o < O) && (op < O);
    if (ok) for (int q = lane; q < ND; q += 64) acc += Q2[o * ND + q] * K2[op * ND + q];
    acc = wave_sum(acc);
    if (lane == 0) F[OF_S + 16 + s] = ok ? acc : 0.f;
  } else if (s < 12) {
    int o = s - 9; bool ok = o < O;
    if (ok) for (int q = lane; q < ND; q += 64) acc += Q2[o * ND + q] * dk[q];
    acc = wave_sum(acc);
    if (lane == 0) F[OF_u + 16 + o] = ok ? acc : 0.f;
  } else if (s < 15) {
    int o = s - 12; bool ok = o < O;
    if (ok) for (int q = lane; q < ND; q += 64) acc += dq[q] * K2[o * ND + q];
    acc = wave_sum(acc);
    if (lane == 0) F[OF_r + 16 + o] = ok ? acc : 0.f;
  } else {
    for (int q = lane; q < ND; q += 64) acc += dq[q] * dk[q];
    acc = wave_sum(acc);
    if (lane == 0) F[OF_w + 16] = acc;
  }
}

__global__ void k_multi(const float* __restrict__ a, const float* __restrict__ bb,
                        const float* __restrict__ bc, float* __restrict__ out)
{
  int i = blockIdx.x * blockDim.x + threadIdx.x;
  if (i >= NB * NM * NM * 2) return;
  int c = i & 1;
  int t = i >> 1;
  int n = t % NM; t /= NM;
  int m = t % NM;
  int b = t / NM;
  out[i] = a[((size_t)b * NM + m) * 2 + c] + bb[((size_t)b * NM + n) * 2 + c] + bc[c];
}

extern "C" void kernel_launch(void* const* d_in, const int* in_sizes, int n_in,
                              void* d_out, int out_size, void* d_ws, size_t ws_size,
                              hipStream_t stream)
{
  const float* key        = (const float*)d_in[0];
  const float* value      = (const float*)d_in[1];
  const float* key_mask   = (const float*)d_in[2];
  const float* value_mask = (const float*)d_in[3];
  const float* w_kt = (const float*)d_in[4];  const float* b_kt = (const float*)d_in[5];
  const float* w_vt = (const float*)d_in[6];  const float* b_vt = (const float*)d_in[7];
  const float* w_km = (const float*)d_in[8];  const float* b_km = (const float*)d_in[9];
  const float* w_vm = (const float*)d_in[10]; const float* b_vm = (const float*)d_in[11];
  const float* w_ks = (const float*)d_in[12]; const float* b_ks = (const float*)d_in[13];
  const float* w_vs = (const float*)d_in[14]; const float* b_vs = (const float*)d_in[15];
  const float* bt_W = (const float*)d_in[16]; const float* bt_lw = (const float*)d_in[17];
  const float* bt_lb = (const float*)d_in[18];
  const float* bi_W = (const float*)d_in[19]; const float* bi_lw = (const float*)d_in[20];
  const float* bi_lb = (const float*)d_in[21];
  const float* w_ffnt = (const float*)d_in[22]; const float* b_ffnt = (const float*)d_in[23];
  const float* w_ffn  = (const float*)d_in[24]; const float* b_ffn  = (const float*)d_in[25];
  const float* qkvt_w = (const float*)d_in[26]; const float* qkvt_b = (const float*)d_in[27];
  const float* qkv_w  = (const float*)d_in[28]; const float* qkv_b  = (const float*)d_in[29];
  const float* w_cls  = (const float*)d_in[30]; const float* b_cls  = (const float*)d_in[31];

  float* ws = (float*)d_ws;
  size_t off = 0;
  auto alloc = [&](size_t nfloat) { float* p = ws + off; off += (nfloat + 3) & ~(size_t)3; return p; };

  float* kt_t = alloc((size_t)NB * NM * ND);
  float* vt_t = alloc((size_t)NB * NNV * ND);
  float* kt_s = alloc((size_t)NB * NM * ND);
  float* vt_s = alloc((size_t)NB * NM * ND);
  float* kmf  = alloc((size_t)NB * NM * ND);
  float* vmf  = alloc((size_t)NB * NM * ND);
  float* linK_t = alloc((size_t)NB * NM * 3);
  float* linV_t = alloc((size_t)NB * NNV * 3);
  float* linK_s = alloc((size_t)NB * NM * 2);
  float* linV_s = alloc((size_t)NB * NM * 2);
  float* fold_t = alloc(FOLD_SZ);
  float* fold_s = alloc(FOLD_SZ);
  float* km2 = alloc((size_t)NB * NM);
  float* a2  = alloc((size_t)NB * NM * 2);
  float* b2  = alloc((size_t)NB * NM * 2);
  float* Lg  = alloc((size_t)NB * NM * NNV * 3);
  float* Yg  = alloc((size_t)NB * NM * NNV * 3);
  u16* WtH = (u16*)alloc((size_t)5 * ND * ND / 2);
  u16* WtL = (u16*)alloc((size_t)5 * ND * ND / 2);
  u16* keyH_t = (u16*)alloc((size_t)NB * NM * ND / 2);
  u16* keyL_t = (u16*)alloc((size_t)NB * NM * ND / 2);
  u16* keyH_s = (u16*)alloc((size_t)NB * NM * ND / 2);
  u16* keyL_s = (u16*)alloc((size_t)NB * NM * ND / 2);
  u16* valH_t = (u16*)alloc((size_t)NB * NNV * ND / 2);
  u16* valL_t = (u16*)alloc((size_t)NB * NNV * ND / 2);
  u16* valH_s = (u16*)alloc((size_t)NB * NM * ND / 2);
  u16* valL_s = (u16*)alloc((size_t)NB * NM * ND / 2);
  (void)ws_size; (void)in_sizes; (void)n_in; (void)out_size;

  u16* tmpH = (u16*)kt_t;
  u16* tmpL = (u16*)(kt_t + 1474560);

  float* out_type   = (float*)d_out;
  float* out_multi  = out_type + (size_t)NB * NM * NNV * 3;
  float* out_single = out_multi + (size_t)NB * NM * NM * 2;

  dim3 blk(256);

  // 1. W^T planes for the 5 biaffine matrices
  k_cvtT<<<dim3(15, 15, 5), blk, 0, stream>>>(bt_W, bi_W, WtH, WtL);

  // 2. all 6 big projections (on-fly split, plane epilogues for c0..c3)
  Proj6 P;
  P.c[0] = { key,   w_kt, b_kt, kt_t, keyH_t, keyL_t, NB * NM,  0, NM,  NM * NH };
  P.c[1] = { value, w_vt, b_vt, vt_t, valH_t, valL_t, NB * NNV, 0, NNV, NNV * NH };
  P.c[2] = { key,   w_ks, b_ks, kt_s, keyH_s, keyL_s, NB * NM,  0, NM,  NM * NH };
  P.c[3] = { value, w_vs, b_vs, vt_s, valH_s, valL_s, NB * NM,  1, NM,  NNV * NH };
  P.c[4] = { key,   w_km, b_km, kmf,  nullptr, nullptr, NB * NM, 0, NM, NM * NH };
  P.c[5] = { value, w_vm, b_vm, vmf,  nullptr, nullptr, NB * NM, 1, NM, NNV * NH };
  k_projM<<<dim3(193 * 10), blk, 0, stream>>>(P, NH);

  // 3-5. folds
  FoldCfg ft = { w_ffnt, b_ffnt, qkvt_w, qkvt_b, fold_t, 3 };
  FoldCfg fs = { w_ffn,  b_ffn,  qkv_w,  qkv_b,  fold_s, 2 };
  k_fold1B<<<dim3(360, 2), blk, 0, stream>>>(ft, fs);
  k_fold2B<<<dim3(364, 2), blk, 0, stream>>>(ft, fs);
  k_fold3B<<<dim3(4, 2), blk, 0, stream>>>(ft, fs);

  // 6. all small matvecs (initial linK/linV for both paths + a2/b2)
  SpCfg s0 = { kt_t, bt_lw, linK_t, NB * NM,  3, 2 * ND, 0 };
  SpCfg s1 = { vt_t, bt_lw, linV_t, NB * NNV, 3, 2 * ND, ND };
  SpCfg s2 = { kt_s, bi_lw, linK_s, NB * NM,  2, 2 * ND, 0 };
  SpCfg s3 = { vt_s, bi_lw, linV_s, NB * NM,  2, 2 * ND, ND };
  SpCfg s4 = { kmf,  w_cls, a2,     NB * NM,  2, 2 * ND, 0 };
  SpCfg s5 = { vmf,  w_cls, b2,     NB * NM,  2, 2 * ND, ND };
  k_sproj6<<<dim3((NB * NNV * 3 + 3) / 4, 6), blk, 0, stream>>>(s0, s1, s2, s3, s4, s5);

  // 7. multi logits
  k_multi<<<dim3((NB * NM * NM * 2 + 255) / 256), blk, 0, stream>>>(a2, b2, b_cls, out_multi);

  // 8. both round-pipelines + type decision
  CoopP cp;
  cp.pa = { WtH, WtL, keyH_t, keyL_t, valH_t, valL_t,
            key_mask, value_mask, 0, NNV,
            fold_t, bt_lw, bt_lb, linK_t, linV_t, out_type, 3, NNV, 5 };
  cp.pb = { WtH + (size_t)3 * ND * ND, WtL + (size_t)3 * ND * ND,
            keyH_s, keyL_s, valH_s, valL_s,
            km2, value_mask, 1, NNV,
            fold_s, bi_lw, bi_lb, linK_s, linV_s, out_single, 2, NM, 4 };
  cp.tmpH = tmpH; cp.tmpL = tmpL;
  cp.Lg = Lg; cp.Yg = Yg;
  cp.key_mask = key_mask; cp.km2 = km2;

  // size the cooperative grid against real occupancy, then try; on ANY failure
  // fall back to phase-per-launch (identical math, guaranteed correct).
  int maxB = 0;
  hipError_t qerr = hipOccupancyMaxActiveBlocksPerMultiprocessor(&maxB, (const void*)k_coop, 256, 0);
  int grid = 256;
  if (qerr == hipSuccess && maxB > 0) {
    long cap = (long)maxB * 256;   // 256 CUs on MI355X
    grid = (int)((cap < 512) ? cap : 512);
  }
  void* coopArgs[] = { (void*)&cp };
  hipError_t cerr = hipLaunchCooperativeKernel((void*)k_coop, dim3(grid), dim3(256), coopArgs, 0, stream);
  if (cerr != hipSuccess) {
    dim3 g2(512);
    for (int path = 0; path < 2; ++path) {
      for (int r = 0; r < 5; ++r) {
        int fin = (r == 4) ? 1 : 0;
        k_phase<<<g2, blk, 0, stream>>>(cp, path, 0, fin);
        k_phase<<<g2, blk, 0, stream>>>(cp, path, 1, fin);
        if (!fin) {
          k_phase<<<g2, blk, 0, stream>>>(cp, path, 2, 0);
          k_phase<<<g2, blk, 0, stream>>>(cp, path, 3, 0);
          k_phase<<<g2, blk, 0, stream>>>(cp, path, 4, 0);
        }
      }
      if (path == 0) k_phase<<<g2, blk, 0, stream>>>(cp, 0, 5, 0);
    }
  }
}

// Round 10
// 1272.062 us; speedup vs baseline: 3.2778x; 2.6971x over previous
//
#include <hip/hip_runtime.h>
#include <math.h>

// ---------------- problem constants ----------------
constexpr int NB = 32;    // B
constexpr int NM = 64;    // M
constexpr int NNV = 65;   // NV
constexpr int NH = 960;   // H
constexpr int ND = 480;   // D
constexpr float ATT_SCALE = 0.045643546458763842f;  // D^-0.5

constexpr int OF_Pq = 0;
constexpr int OF_cq = 4320;
constexpr int OF_Q2 = 5760;
constexpr int OF_V2 = OF_Q2 + 2*1440;
constexpr int OF_dq = 10080;
constexpr int OF_dv = OF_dq + 2*480;
constexpr int OF_S  = 11520;
constexpr int OF_u  = 11529;
constexpr int OF_r  = 11532;
constexpr int OF_w  = 11535;
constexpr int FOLD_SZ = 11552;

typedef float f32x4 __attribute__((ext_vector_type(4)));
typedef short s16x8 __attribute__((ext_vector_type(8)));

__device__ __forceinline__ float wave_sum(float v) {
#pragma unroll
  for (int d = 32; d; d >>= 1) v += __shfl_xor(v, d);
  return v;
}

__device__ __forceinline__ void split_bf16(float x, short& hi, short& lo) {
  union { float f; unsigned u; } a; a.f = x;
  unsigned uh = a.u + 0x7fffu + ((a.u >> 16) & 1u);
  hi = (short)(uh >> 16);
  union { unsigned u; float f; } b; b.u = ((unsigned)(unsigned short)hi) << 16;
  union { float f; unsigned u; } c; c.f = x - b.f;
  unsigned ul = c.u + 0x7fffu + ((c.u >> 16) & 1u);
  lo = (short)(ul >> 16);
}

// ---------------- MFMA split-bf16 projection GEMM (6 configs, XCD swizzled) ----------------
struct ProjCfg {
  const float* X; const float* W; const float* bias; float* C;
  int R; int x0; int rpb; int xbs;
};
struct Proj6 { ProjCfg c[6]; };

constexpr int KP = 40;   // padded k stride (ushorts)

__global__ __launch_bounds__(256) void k_projM(Proj6 P, int K)
{
  __shared__ unsigned short As_hi[64][KP], As_lo[64][KP];
  __shared__ unsigned short Bs_hi[48][KP], Bs_lo[48][KP];
  int p = blockIdx.x, total = gridDim.x;
  int q = total >> 3, r = total & 7;
  int xk = p & 7, idx = p >> 3;
  int lgc = (xk < r) ? (xk * (q + 1) + idx) : (r * (q + 1) + (xk - r) * q + idx);
  int mp = lgc / 10, nx = lgc - mp * 10;
  ProjCfg cfg; int my;
  if      (mp < 32)  { cfg = P.c[0]; my = mp; }
  else if (mp < 65)  { cfg = P.c[1]; my = mp - 32; }
  else if (mp < 97)  { cfg = P.c[2]; my = mp - 65; }
  else if (mp < 129) { cfg = P.c[3]; my = mp - 97; }
  else if (mp < 161) { cfg = P.c[4]; my = mp - 129; }
  else               { cfg = P.c[5]; my = mp - 161; }
  const int m0 = my * 64, n0 = nx * 48;
  const int tid = threadIdx.x;
  const int l6 = tid & 63, w = tid >> 6;
  const int lr = tid >> 2, kc = (tid & 3) * 8;
  const float* Arow = nullptr;
  {
    int rr = m0 + lr;
    if (rr < cfg.R) {
      int b = rr / cfg.rpb, r2 = rr - b * cfg.rpb;
      Arow = cfg.X + (size_t)b * cfg.xbs + (size_t)(cfg.x0 + r2) * K;
    }
  }
  const float* Brow = (lr < 48) ? (cfg.W + (size_t)(n0 + lr) * K) : nullptr;
  const int fr = l6 & 15, fk = (l6 >> 4) * 8;
  f32x4 acc0 = {0.f, 0.f, 0.f, 0.f}, acc1 = acc0, acc2 = acc0;
  for (int k0 = 0; k0 < K; k0 += 32) {
    float xs[8] = {0.f, 0.f, 0.f, 0.f, 0.f, 0.f, 0.f, 0.f};
    if (Arow) {
      float4 a0 = *(const float4*)(Arow + k0 + kc);
      float4 a1 = *(const float4*)(Arow + k0 + kc + 4);
      xs[0] = a0.x; xs[1] = a0.y; xs[2] = a0.z; xs[3] = a0.w;
      xs[4] = a1.x; xs[5] = a1.y; xs[6] = a1.z; xs[7] = a1.w;
    }
    s16x8 vh, vl;
#pragma unroll
    for (int e = 0; e < 8; ++e) { short h, lo2; split_bf16(xs[e], h, lo2); vh[e] = h; vl[e] = lo2; }
    *(s16x8*)&As_hi[lr][kc] = vh;
    *(s16x8*)&As_lo[lr][kc] = vl;
    if (Brow) {
      float4 b0 = *(const float4*)(Brow + k0 + kc);
      float4 b1 = *(const float4*)(Brow + k0 + kc + 4);
      float ys[8] = {b0.x, b0.y, b0.z, b0.w, b1.x, b1.y, b1.z, b1.w};
      s16x8 wh, wl;
#pragma unroll
      for (int e = 0; e < 8; ++e) { short h, lo2; split_bf16(ys[e], h, lo2); wh[e] = h; wl[e] = lo2; }
      *(s16x8*)&Bs_hi[lr][kc] = wh;
      *(s16x8*)&Bs_lo[lr][kc] = wl;
    }
    __syncthreads();
    s16x8 ah = *(const s16x8*)&As_hi[16 * w + fr][fk];
    s16x8 al = *(const s16x8*)&As_lo[16 * w + fr][fk];
    {
      s16x8 bh = *(const s16x8*)&Bs_hi[fr][fk];
      s16x8 bl = *(const s16x8*)&Bs_lo[fr][fk];
      acc0 = __builtin_amdgcn_mfma_f32_16x16x32_bf16(ah, bh, acc0, 0, 0, 0);
      acc0 = __builtin_amdgcn_mfma_f32_16x16x32_bf16(ah, bl, acc0, 0, 0, 0);
      acc0 = __builtin_amdgcn_mfma_f32_16x16x32_bf16(al, bh, acc0, 0, 0, 0);
    }
    {
      s16x8 bh = *(const s16x8*)&Bs_hi[16 + fr][fk];
      s16x8 bl = *(const s16x8*)&Bs_lo[16 + fr][fk];
      acc1 = __builtin_amdgcn_mfma_f32_16x16x32_bf16(ah, bh, acc1, 0, 0, 0);
      acc1 = __builtin_amdgcn_mfma_f32_16x16x32_bf16(ah, bl, acc1, 0, 0, 0);
      acc1 = __builtin_amdgcn_mfma_f32_16x16x32_bf16(al, bh, acc1, 0, 0, 0);
    }
    {
      s16x8 bh = *(const s16x8*)&Bs_hi[32 + fr][fk];
      s16x8 bl = *(const s16x8*)&Bs_lo[32 + fr][fk];
      acc2 = __builtin_amdgcn_mfma_f32_16x16x32_bf16(ah, bh, acc2, 0, 0, 0);
      acc2 = __builtin_amdgcn_mfma_f32_16x16x32_bf16(ah, bl, acc2, 0, 0, 0);
      acc2 = __builtin_amdgcn_mfma_f32_16x16x32_bf16(al, bh, acc2, 0, 0, 0);
    }
    __syncthreads();
  }
#pragma unroll
  for (int c = 0; c < 3; ++c) {
    f32x4 av = (c == 0) ? acc0 : (c == 1) ? acc1 : acc2;
    int n = n0 + 16 * c + fr;
    float bv = cfg.bias[n];
#pragma unroll
    for (int g = 0; g < 4; ++g) {
      int rr = m0 + 16 * w + (l6 >> 4) * 4 + g;
      if (rr < cfg.R) cfg.C[(size_t)rr * ND + n] = av[g] + bv;
    }
  }
}

// ---------------- MFMA split-bf16 tmp GEMM + optional type-decision epilogue ----------------
__global__ __launch_bounds__(256) void k_tmpM(
    const float* __restrict__ Key, const float* __restrict__ W,
    float* __restrict__ T, int O,
    const float* __restrict__ typeSrc, const float* __restrict__ keyMask,
    float* __restrict__ km2, int doType)
{
  __shared__ unsigned short As_hi[64][KP], As_lo[64][KP];
  __shared__ unsigned short Bs_hi[48][KP], Bs_lo[48][KP];
  const int n0 = blockIdx.x * 48;
  const int o = blockIdx.y, b = blockIdx.z;
  const int tid = threadIdx.x;
  // type decision epilogue (independent work, one block-column per batch)
  if (doType && blockIdx.x == 0 && blockIdx.y == 0 && tid < NM) {
    const float* p = typeSrc + ((size_t)(b * NM + tid)) * NNV * 3;
    float l0 = p[0], l1 = p[1], l2 = p[2];
    int arg = 0; float best = l0;
    if (l1 > best) { best = l1; arg = 1; }
    if (l2 > best) { arg = 2; }
    km2[b * NM + tid] = (keyMask[b * NM + tid] != 0.f && arg == 1) ? 1.f : 0.f;
  }
  const int l6 = tid & 63, w = tid >> 6;
  const int lr = tid >> 2, kc = (tid & 3) * 8;
  const float* Arow = Key + (size_t)b * NM * ND + (size_t)lr * ND;
  const float* Wo = W + (size_t)o * ND * ND;
  const int fr = l6 & 15, fk = (l6 >> 4) * 8;
  f32x4 acc0 = {0.f, 0.f, 0.f, 0.f}, acc1 = acc0, acc2 = acc0;
  for (int k0 = 0; k0 < ND; k0 += 32) {
    {
      float4 a0 = *(const float4*)(Arow + k0 + kc);
      float4 a1 = *(const float4*)(Arow + k0 + kc + 4);
      float xs[8] = {a0.x, a0.y, a0.z, a0.w, a1.x, a1.y, a1.z, a1.w};
      s16x8 vh, vl;
#pragma unroll
      for (int e = 0; e < 8; ++e) { short h, lo2; split_bf16(xs[e], h, lo2); vh[e] = h; vl[e] = lo2; }
      *(s16x8*)&As_hi[lr][kc] = vh;
      *(s16x8*)&As_lo[lr][kc] = vl;
    }
    if (lr < 48) {   // transpose-stage B: Bs[n][k] <- W[k][n]
      s16x8 wh, wl;
#pragma unroll
      for (int e = 0; e < 8; ++e) {
        float x = Wo[(size_t)(k0 + kc + e) * ND + n0 + lr];
        short h, lo2; split_bf16(x, h, lo2); wh[e] = h; wl[e] = lo2;
      }
      *(s16x8*)&Bs_hi[lr][kc] = wh;
      *(s16x8*)&Bs_lo[lr][kc] = wl;
    }
    __syncthreads();
    s16x8 ah = *(const s16x8*)&As_hi[16 * w + fr][fk];
    s16x8 al = *(const s16x8*)&As_lo[16 * w + fr][fk];
    {
      s16x8 bh = *(const s16x8*)&Bs_hi[fr][fk];
      s16x8 bl = *(const s16x8*)&Bs_lo[fr][fk];
      acc0 = __builtin_amdgcn_mfma_f32_16x16x32_bf16(ah, bh, acc0, 0, 0, 0);
      acc0 = __builtin_amdgcn_mfma_f32_16x16x32_bf16(ah, bl, acc0, 0, 0, 0);
      acc0 = __builtin_amdgcn_mfma_f32_16x16x32_bf16(al, bh, acc0, 0, 0, 0);
    }
    {
      s16x8 bh = *(const s16x8*)&Bs_hi[16 + fr][fk];
      s16x8 bl = *(const s16x8*)&Bs_lo[16 + fr][fk];
      acc1 = __builtin_amdgcn_mfma_f32_16x16x32_bf16(ah, bh, acc1, 0, 0, 0);
      acc1 = __builtin_amdgcn_mfma_f32_16x16x32_bf16(ah, bl, acc1, 0, 0, 0);
      acc1 = __builtin_amdgcn_mfma_f32_16x16x32_bf16(al, bh, acc1, 0, 0, 0);
    }
    {
      s16x8 bh = *(const s16x8*)&Bs_hi[32 + fr][fk];
      s16x8 bl = *(const s16x8*)&Bs_lo[32 + fr][fk];
      acc2 = __builtin_amdgcn_mfma_f32_16x16x32_bf16(ah, bh, acc2, 0, 0, 0);
      acc2 = __builtin_amdgcn_mfma_f32_16x16x32_bf16(ah, bl, acc2, 0, 0, 0);
      acc2 = __builtin_amdgcn_mfma_f32_16x16x32_bf16(al, bh, acc2, 0, 0, 0);
    }
    __syncthreads();
  }
  float* C = T + ((size_t)(b * O + o) * NM) * ND;
#pragma unroll
  for (int c = 0; c < 3; ++c) {
    f32x4 av = (c == 0) ? acc0 : (c == 1) ? acc1 : acc2;
    int n = n0 + 16 * c + fr;
#pragma unroll
    for (int g = 0; g < 4; ++g) {
      int rr = 16 * w + (l6 >> 4) * 4 + g;
      C[(size_t)rr * ND + n] = av[g];
    }
  }
}

// fused bilinear + attention(MODE0) per (b,m) with parallel softmax
template <int O, int NVX>
__global__ __launch_bounds__(256) void k_bilatt0(
    const float* __restrict__ T, const float* __restrict__ Val,
    const float* __restrict__ linK, const float* __restrict__ linV,
    const float* __restrict__ lb, const float* __restrict__ F,
    const float* __restrict__ km, const float* __restrict__ vm,
    int vmOff, int vmStride, float* __restrict__ Y1)
{
  __shared__ float Ls[NVX][3];
  __shared__ float STs[NVX][3];
  __shared__ float hs[NVX], gs[NVX], mkj[NVX];
  __shared__ float Pm[NVX][66];
  __shared__ float rmx[NVX][3];
  __shared__ float rsum[NVX][3];
  __shared__ float ry[NVX][3][3];
  __shared__ float lvs[NVX][3];
  const int b = blockIdx.x >> 6, m = blockIdx.x & 63;
  const int tid = threadIdx.x;
  const int lane = tid & 63, w = tid >> 6;

  for (int j = tid; j < NVX; j += 256) {
    mkj[j] = vm[b * vmStride + vmOff + j];
#pragma unroll
    for (int o = 0; o < O; ++o) lvs[j][o] = linV[((size_t)b * NVX + j) * O + o];
  }
  float4 tsr[O][2];
#pragma unroll
  for (int o = 0; o < O; ++o) {
    const float4* trow = (const float4*)(T + (((size_t)b * O + o) * NM + m) * (size_t)ND);
    tsr[o][0] = trow[lane];
    tsr[o][1] = (lane < 56) ? trow[64 + lane] : make_float4(0.f, 0.f, 0.f, 0.f);
  }
  float lk[O];
#pragma unroll
  for (int o = 0; o < O; ++o) lk[o] = linK[((size_t)b * NM + m) * O + o] + lb[o];
  const float gm = km[b * NM + m];
  const bool gz = (gm == 0.f);

  for (int n = w; n < NVX; n += 4) {
    const float4* vrow = (const float4*)(Val + ((size_t)b * NVX + n) * (size_t)ND);
    float4 v0 = vrow[lane];
    float4 v1 = (lane < 56) ? vrow[64 + lane] : make_float4(0.f, 0.f, 0.f, 0.f);
    float a[3] = {0.f, 0.f, 0.f};
#pragma unroll
    for (int o = 0; o < O; ++o) {
      a[o] = v0.x * tsr[o][0].x + v0.y * tsr[o][0].y + v0.z * tsr[o][0].z + v0.w * tsr[o][0].w
           + v1.x * tsr[o][1].x + v1.y * tsr[o][1].y + v1.z * tsr[o][1].z + v1.w * tsr[o][1].w;
    }
#pragma unroll
    for (int o = 0; o < O; ++o) a[o] = wave_sum(a[o]);
    if (lane == 0) {
#pragma unroll
      for (int o = 0; o < O; ++o) Ls[n][o] = a[o] + lk[o] + lvs[n][o];
      if (O == 2) Ls[n][2] = 0.f;
    }
  }
  __syncthreads();
  const float* Sm = F + OF_S;
  const float u0 = F[OF_u], u1 = F[OF_u + 1], u2 = F[OF_u + 2];
  const float r0 = F[OF_r], r1 = F[OF_r + 1], r2 = F[OF_r + 2];
  const float wc = F[OF_w];
  if (tid < NVX) {
    int j = tid;
    float t0 = Ls[j][0], t1 = Ls[j][1], t2 = Ls[j][2];
    STs[j][0] = t0 * Sm[0] + t1 * Sm[3] + t2 * Sm[6];
    STs[j][1] = t0 * Sm[1] + t1 * Sm[4] + t2 * Sm[7];
    STs[j][2] = t0 * Sm[2] + t1 * Sm[5] + t2 * Sm[8];
    hs[j] = t0 * u0 + t1 * u1 + t2 * u2;
    gs[j] = t0 * r0 + t1 * r1 + t2 * r2;
  }
  __syncthreads();
  const bool act = tid < NVX * 3;
  int i = 0, qq = 0, jlo = 0, jhi = 0;
  float st0 = 0, st1 = 0, st2 = 0, hi = 0;
  bool rowz = true;
  if (act) {
    i = tid / 3; qq = tid - i * 3;
    jlo = qq * 22; jhi = (jlo + 22 < NVX) ? jlo + 22 : NVX;
    st0 = STs[i][0]; st1 = STs[i][1]; st2 = STs[i][2]; hi = hs[i];
    rowz = gz || (mkj[i] == 0.f);
    float mx = -3.0e38f;
    for (int j = jlo; j < jhi; ++j) {
      float s = st0 * Ls[j][0] + st1 * Ls[j][1] + hi + gs[j] + wc;
      if (O == 3) s += st2 * Ls[j][2];
      s = (rowz || mkj[j] == 0.f) ? -10000.f : ATT_SCALE * s;
      Pm[i][j] = s;
      mx = fmaxf(mx, s);
    }
    rmx[i][qq] = mx;
  }
  __syncthreads();
  if (act) {
    float mx = fmaxf(fmaxf(rmx[i][0], rmx[i][1]), rmx[i][2]);
    float sum = 0.f, y0 = 0.f, y1 = 0.f, y2 = 0.f;
    for (int j = jlo; j < jhi; ++j) {
      float pp = __expf(Pm[i][j] - mx);
      sum += pp; y0 += pp * Ls[j][0]; y1 += pp * Ls[j][1];
      if (O == 3) y2 += pp * Ls[j][2];
    }
    rsum[i][qq] = sum; ry[i][qq][0] = y0; ry[i][qq][1] = y1; ry[i][qq][2] = y2;
  }
  __syncthreads();
  if (tid < NVX) {
    int ii = tid;
    float sum = rsum[ii][0] + rsum[ii][1] + rsum[ii][2];
    float y0 = ry[ii][0][0] + ry[ii][1][0] + ry[ii][2][0];
    float y1 = ry[ii][0][1] + ry[ii][1][1] + ry[ii][2][1];
    float y2 = ry[ii][0][2] + ry[ii][1][2] + ry[ii][2][2];
    float inv = 1.f / sum;
    size_t ob = (((size_t)b * NM + m) * NVX + ii) * O;
    Y1[ob + 0] = y0 * inv;
    Y1[ob + 1] = y1 * inv;
    if (O == 3) Y1[ob + 2] = y2 * inv;
  }
}

// ---- merged att1 + value-update + key-update kernel ----
// blocks 0..NVX-1 per b: att1 column n + value row update + linV (old k_att1vupd)
// blocks NVX..NVX+NM-1 per b: recompute Y2 column m + key row update + linK (old k_kupd)
template <int O, int NVX>
__global__ __launch_bounds__(256) void k_updB(
    const float* __restrict__ Y1, const float* __restrict__ F,
    const float* __restrict__ km, const float* __restrict__ vm,
    int vmOff, int vmStride,
    float* __restrict__ keyb, float* __restrict__ valb,
    const float* __restrict__ lw,
    float* __restrict__ linK, float* __restrict__ linV)
{
  __shared__ float Ys1[NM][3];
  __shared__ float STs[NM][3];
  __shared__ float hs[NM], gs[NM], mkm[NM];
  __shared__ float Pm[NM][66];
  __shared__ float rmx[NM][3], rsum[NM][3], ry[NM][3][3];
  __shared__ float Ys2[NVX][3];
  __shared__ float drow[ND];
  constexpr int RT = NVX + NM;
  const int b = blockIdx.x / RT, rr = blockIdx.x - b * RT;
  const int tid = threadIdx.x;
  const float* V2 = F + OF_V2;
  const float* dvp = F + OF_dv;
  const float* Sm = F + OF_S + 16;
  const float u0 = F[OF_u + 16], u1 = F[OF_u + 17], u2 = F[OF_u + 18];
  const float r0 = F[OF_r + 16], r1 = F[OF_r + 17], r2 = F[OF_r + 18];
  const float wc = F[OF_w + 16];
  if (tid < NM) mkm[tid] = km[b * NM + tid];

  if (rr < NVX) {
    // ===================== n-row: att1 + vupd + linV =====================
    const int n = rr;
    for (int u = tid; u < NM * O; u += 256) {
      int mm = u % NM, o = u / NM;
      Ys1[mm][o] = Y1[(((size_t)b * NM + mm) * NVX + n) * O + o];
    }
    if (tid < NM && O == 2) Ys1[tid][2] = 0.f;
    const float gm = vm[b * vmStride + vmOff + n];
    const bool gz = (gm == 0.f);
    __syncthreads();
    if (tid < NM) {
      int j = tid;
      float t0 = Ys1[j][0], t1 = Ys1[j][1], t2 = Ys1[j][2];
      STs[j][0] = t0 * Sm[0] + t1 * Sm[3] + t2 * Sm[6];
      STs[j][1] = t0 * Sm[1] + t1 * Sm[4] + t2 * Sm[7];
      STs[j][2] = t0 * Sm[2] + t1 * Sm[5] + t2 * Sm[8];
      hs[j] = t0 * u0 + t1 * u1 + t2 * u2;
      gs[j] = t0 * r0 + t1 * r1 + t2 * r2;
    }
    __syncthreads();
    const bool act = tid < NM * 3;
    int i = 0, qq = 0, jlo = 0, jhi = 0;
    float st0 = 0, st1 = 0, st2 = 0, hi = 0;
    bool rowz = true;
    if (act) {
      i = tid / 3; qq = tid - i * 3;
      jlo = qq * 22; jhi = (jlo + 22 < NM) ? jlo + 22 : NM;
      st0 = STs[i][0]; st1 = STs[i][1]; st2 = STs[i][2]; hi = hs[i];
      rowz = gz || (mkm[i] == 0.f);
      float mx = -3.0e38f;
      for (int j = jlo; j < jhi; ++j) {
        float s = st0 * Ys1[j][0] + st1 * Ys1[j][1] + hi + gs[j] + wc;
        if (O == 3) s += st2 * Ys1[j][2];
        s = (rowz || mkm[j] == 0.f) ? -10000.f : ATT_SCALE * s;
        Pm[i][j] = s;
        mx = fmaxf(mx, s);
      }
      rmx[i][qq] = mx;
    }
    __syncthreads();
    if (act) {
      float mx = fmaxf(fmaxf(rmx[i][0], rmx[i][1]), rmx[i][2]);
      float sum = 0.f, y0 = 0.f, y1 = 0.f, y2 = 0.f;
      for (int j = jlo; j < jhi; ++j) {
        float pp = __expf(Pm[i][j] - mx);
        sum += pp; y0 += pp * Ys1[j][0]; y1 += pp * Ys1[j][1];
        if (O == 3) y2 += pp * Ys1[j][2];
      }
      rsum[i][qq] = sum; ry[i][qq][0] = y0; ry[i][qq][1] = y1; ry[i][qq][2] = y2;
    }
    __syncthreads();
    if (tid < NM) {
      int ii = tid;
      float sum = rsum[ii][0] + rsum[ii][1] + rsum[ii][2];
      float y0 = ry[ii][0][0] + ry[ii][1][0] + ry[ii][2][0];
      float y1 = ry[ii][0][1] + ry[ii][1][1] + ry[ii][2][1];
      float y2 = ry[ii][0][2] + ry[ii][1][2] + ry[ii][2][2];
      float inv = 1.f / sum;
      Ys2[ii][0] = y0 * inv; Ys2[ii][1] = y1 * inv;
      Ys2[ii][2] = (O == 3) ? y2 * inv : 0.f;
    }
    __syncthreads();
    for (int d = tid; d < ND; d += 256) {
      float v0 = V2[d], v1 = V2[ND + d], v2 = (O == 3) ? V2[2 * ND + d] : 0.f;
      float mx = -3.0e38f;
      for (int j = 0; j < NM; ++j) {
        float s = Ys2[j][0] * v0 + Ys2[j][1] * v1;
        if (O == 3) s += Ys2[j][2] * v2;
        mx = fmaxf(mx, s);
      }
      size_t di = ((size_t)b * NVX + n) * ND + d;
      float nv = valb[di] + mx + dvp[d];
      valb[di] = nv;
      drow[d] = nv;
    }
    __syncthreads();
    const int wv = tid >> 6, lane = tid & 63;
    if (wv < O) {
      float acc = 0.f;
      for (int d = lane; d < ND; d += 64) acc += drow[d] * lw[(size_t)wv * 2 * ND + ND + d];
      acc = wave_sum(acc);
      if (lane == 0) linV[((size_t)b * NVX + n) * O + wv] = acc;
    }
  } else {
    // ===================== m-row: recompute Y2 column m + kupd + linK =====================
    const int m = rr - NVX;
    __syncthreads();
    const float qm = mkm[m];
    for (int n = tid; n < NVX; n += 256) {
      float gmv = vm[b * vmStride + vmOff + n];
      bool rowz = (gmv == 0.f) || (qm == 0.f);
      size_t mi = (((size_t)b * NM + m) * NVX + n) * O;
      float Yi0 = Y1[mi], Yi1 = Y1[mi + 1], Yi2 = (O == 3) ? Y1[mi + 2] : 0.f;
      float st0 = Yi0 * Sm[0] + Yi1 * Sm[3] + Yi2 * Sm[6];
      float st1 = Yi0 * Sm[1] + Yi1 * Sm[4] + Yi2 * Sm[7];
      float st2 = Yi0 * Sm[2] + Yi1 * Sm[5] + Yi2 * Sm[8];
      float hi = Yi0 * u0 + Yi1 * u1 + Yi2 * u2;
      float mx = -3.0e38f, sum = 0.f, y0 = 0.f, y1 = 0.f, y2 = 0.f;
      for (int j = 0; j < NM; ++j) {
        size_t ji = (((size_t)b * NM + j) * NVX + n) * O;
        float t0 = Y1[ji], t1 = Y1[ji + 1], t2 = (O == 3) ? Y1[ji + 2] : 0.f;
        float s = st0 * t0 + st1 * t1 + st2 * t2 + hi
                + (t0 * r0 + t1 * r1 + t2 * r2) + wc;
        s = (rowz || mkm[j] == 0.f) ? -10000.f : ATT_SCALE * s;
        float nm2 = fmaxf(mx, s);
        float pp = __expf(s - nm2), cg = __expf(mx - nm2);
        sum = sum * cg + pp; y0 = y0 * cg + pp * t0; y1 = y1 * cg + pp * t1; y2 = y2 * cg + pp * t2;
        mx = nm2;
      }
      float inv = 1.f / sum;
      Ys2[n][0] = y0 * inv; Ys2[n][1] = y1 * inv;
      Ys2[n][2] = (O == 3) ? y2 * inv : 0.f;
    }
    __syncthreads();
    for (int d = tid; d < ND; d += 256) {
      float v0 = V2[d], v1 = V2[ND + d], v2 = (O == 3) ? V2[2 * ND + d] : 0.f;
      float mx = -3.0e38f;
      for (int j = 0; j < NVX; ++j) {
        float s = Ys2[j][0] * v0 + Ys2[j][1] * v1;
        if (O == 3) s += Ys2[j][2] * v2;
        mx = fmaxf(mx, s);
      }
      size_t di = ((size_t)b * NM + m) * ND + d;
      float nv = keyb[di] + mx + dvp[d];
      keyb[di] = nv;
      drow[d] = nv;
    }
    __syncthreads();
    const int wv = tid >> 6, lane = tid & 63;
    if (wv < O) {
      float acc = 0.f;
      for (int d = lane; d < ND; d += 64) acc += drow[d] * lw[(size_t)wv * 2 * ND + d];
      acc = wave_sum(acc);
      if (lane == 0) linK[((size_t)b * NM + m) * O + wv] = acc;
    }
  }
}

// final bilinear with mask, register-ts + global Val
template <int O, int NVX>
__global__ __launch_bounds__(256) void k_bilfin(
    const float* __restrict__ T, const float* __restrict__ Val,
    const float* __restrict__ linK, const float* __restrict__ linV,
    const float* __restrict__ lb, const float* __restrict__ km,
    const float* __restrict__ vm, int vmOff, int vmStride,
    float* __restrict__ Out)
{
  const int b = blockIdx.x >> 6, m = blockIdx.x & 63;
  const int tid = threadIdx.x;
  const int lane = tid & 63, w = tid >> 6;
  float4 tsr[O][2];
#pragma unroll
  for (int o = 0; o < O; ++o) {
    const float4* trow = (const float4*)(T + (((size_t)b * O + o) * NM + m) * (size_t)ND);
    tsr[o][0] = trow[lane];
    tsr[o][1] = (lane < 56) ? trow[64 + lane] : make_float4(0.f, 0.f, 0.f, 0.f);
  }
  float lk[O];
#pragma unroll
  for (int o = 0; o < O; ++o) lk[o] = linK[((size_t)b * NM + m) * O + o] + lb[o];
  const float kmv = km[b * NM + m];
  for (int n = w; n < NVX; n += 4) {
    const float4* vrow = (const float4*)(Val + ((size_t)b * NVX + n) * (size_t)ND);
    float4 v0 = vrow[lane];
    float4 v1 = (lane < 56) ? vrow[64 + lane] : make_float4(0.f, 0.f, 0.f, 0.f);
    float a[3] = {0.f, 0.f, 0.f};
#pragma unroll
    for (int o = 0; o < O; ++o) {
      a[o] = v0.x * tsr[o][0].x + v0.y * tsr[o][0].y + v0.z * tsr[o][0].z + v0.w * tsr[o][0].w
           + v1.x * tsr[o][1].x + v1.y * tsr[o][1].y + v1.z * tsr[o][1].z + v1.w * tsr[o][1].w;
    }
#pragma unroll
    for (int o = 0; o < O; ++o) a[o] = wave_sum(a[o]);
    if (lane == 0) {
      float msk = kmv * vm[b * vmStride + vmOff + n];
      size_t ob = (((size_t)b * NM + m) * NVX + n) * O;
#pragma unroll
      for (int o = 0; o < O; ++o)
        Out[ob + o] = (a[o] + lk[o] + linV[((size_t)b * NVX + n) * O + o]) * msk;
    }
  }
}

// batched small matvec
struct SpCfg { const float* X; const float* W; float* Out; int R; int O; int wStride; int wOff; };
__global__ __launch_bounds__(256) void k_sproj6(
    SpCfg s0, SpCfg s1, SpCfg s2, SpCfg s3, SpCfg s4, SpCfg s5)
{
  int z = blockIdx.y;
  SpCfg c = (z == 0) ? s0 : (z == 1) ? s1 : (z == 2) ? s2 : (z == 3) ? s3 : (z == 4) ? s4 : s5;
  int gid = blockIdx.x * 4 + (threadIdx.x >> 6);
  if (gid >= c.R * c.O) return;
  int lane = threadIdx.x & 63;
  int r = gid / c.O, o = gid - r * c.O;
  const float* x = c.X + (size_t)r * ND;
  const float* wp = c.W + (size_t)o * c.wStride + c.wOff;
  float acc = 0.f;
  for (int d = lane; d < ND; d += 64) acc += x[d] * wp[d];
  acc = wave_sum(acc);
  if (lane == 0) c.Out[gid] = acc;
}

// ---------------- folds ----------------
struct FoldCfg { const float* fw; const float* fb; const float* qw; const float* qb; float* F; int O; };

__global__ __launch_bounds__(256) void k_fold1B(FoldCfg A, FoldCfg Bc)
{
  FoldCfg c = (blockIdx.y == 0) ? A : Bc;
  int O = c.O;
  int gid = blockIdx.x * 4 + (threadIdx.x >> 6);
  int lane = threadIdx.x & 63;
  if (gid >= 3 * ND) return;
  int part = gid / ND, cc0 = gid - part * ND;
  const float* qrow = c.qw + (size_t)(part * ND + cc0) * ND;
  float p0 = 0.f, p1 = 0.f, p2 = 0.f, cc = 0.f;
  for (int d = lane; d < ND; d += 64) {
    float q = qrow[d];
    p0 += c.fw[d * O + 0] * q;
    p1 += c.fw[d * O + 1] * q;
    if (O == 3) p2 += c.fw[d * O + 2] * q;
    cc += c.fb[d] * q;
  }
  p0 = wave_sum(p0); p1 = wave_sum(p1); p2 = wave_sum(p2); cc = wave_sum(cc);
  if (lane == 0) {
    c.F[OF_Pq + part * 1440 + 0 * ND + cc0] = p0;
    c.F[OF_Pq + part * 1440 + 1 * ND + cc0] = p1;
    c.F[OF_Pq + part * 1440 + 2 * ND + cc0] = (O == 3) ? p2 : 0.f;
    c.F[OF_cq + part * ND + cc0] = cc + c.qb[part * ND + cc0];
  }
}

__global__ __launch_bounds__(256) void k_fold2B(FoldCfg A, FoldCfg Bc)
{
  FoldCfg c = (blockIdx.y == 0) ? A : Bc;
  int O = c.O;
  float* F = c.F;
  int gid = blockIdx.x * 4 + (threadIdx.x >> 6);
  int lane = threadIdx.x & 63;
  if (gid < 3 * ND) {
    int part = gid / ND, cc0 = gid - part * ND;
    const float* qrow = c.qw + (size_t)(part * ND + cc0) * ND;
    const float* Pv = F + OF_Pq + 2 * 1440;
    const float* cv = F + OF_cq + 2 * ND;
    float p0 = 0.f, p1 = 0.f, p2 = 0.f, cc = 0.f;
    for (int d = lane; d < ND; d += 64) {
      float q = qrow[d];
      p0 += Pv[0 * ND + d] * q;
      p1 += Pv[1 * ND + d] * q;
      if (O == 3) p2 += Pv[2 * ND + d] * q;
      cc += cv[d] * q;
    }
    p0 = wave_sum(p0); p1 = wave_sum(p1); p2 = wave_sum(p2); cc = wave_sum(cc);
    if (lane == 0) {
      F[OF_Q2 + part * 1440 + 0 * ND + cc0] = p0;
      F[OF_Q2 + part * 1440 + 1 * ND + cc0] = p1;
      F[OF_Q2 + part * 1440 + 2 * ND + cc0] = (O == 3) ? p2 : 0.f;
      F[OF_dq + part * ND + cc0] = cc + c.qb[part * ND + cc0];
    }
  } else if (gid < 3 * ND + 16) {
    int s = gid - 3 * ND;
    const float* Pq = F + OF_Pq;
    const float* Pk = F + OF_Pq + 1440;
    const float* cq = F + OF_cq;
    const float* ck = F + OF_cq + ND;
    float acc = 0.f;
    if (s < 9) {
      int o = s / 3, op = s % 3;
      bool ok = (o < O) && (op < O);
      if (ok) for (int q = lane; q < ND; q += 64) acc += Pq[o * ND + q] * Pk[op * ND + q];
      acc = wave_sum(acc);
      if (lane == 0) F[OF_S + s] = ok ? acc : 0.f;
    } else if (s < 12) {
      int o = s - 9; bool ok = o < O;
      if (ok) for (int q = lane; q < ND; q += 64) acc += Pq[o * ND + q] * ck[q];
      acc = wave_sum(acc);
      if (lane == 0) F[OF_u + o] = ok ? acc : 0.f;
    } else if (s < 15) {
      int o = s - 12; bool ok = o < O;
      if (ok) for (int q = lane; q < ND; q += 64) acc += cq[q] * Pk[o * ND + q];
      acc = wave_sum(acc);
      if (lane == 0) F[OF_r + o] = ok ? acc : 0.f;
    } else {
      for (int q = lane; q < ND; q += 64) acc += cq[q] * ck[q];
      acc = wave_sum(acc);
      if (lane == 0) F[OF_w] = acc;
    }
  }
}

__global__ __launch_bounds__(256) void k_fold3B(FoldCfg A, FoldCfg Bc)
{
  FoldCfg c = (blockIdx.y == 0) ? A : Bc;
  int O = c.O;
  float* F = c.F;
  int s = blockIdx.x * 4 + (threadIdx.x >> 6);
  int lane = threadIdx.x & 63;
  if (s >= 16) return;
  const float* Q2 = F + OF_Q2;
  const float* K2 = F + OF_Q2 + 1440;
  const float* dq = F + OF_dq;
  const float* dk = F + OF_dq + ND;
  float acc = 0.f;
  if (s < 9) {
    int o = s / 3, op = s % 3;
    bool ok = (o < O) && (op < O);
    if (ok) for (int q = lane; q < ND; q += 64) acc += Q2[o * ND + q] * K2[op * ND + q];
    acc = wave_sum(acc);
    if (lane == 0) F[OF_S + 16 + s] = ok ? acc : 0.f;
  } else if (s < 12) {
    int o = s - 9; bool ok = o < O;
    if (ok) for (int q = lane; q < ND; q += 64) acc += Q2[o * ND + q] * dk[q];
    acc = wave_sum(acc);
    if (lane == 0) F[OF_u + 16 + o] = ok ? acc : 0.f;
  } else if (s < 15) {
    int o = s - 12; bool ok = o < O;
    if (ok) for (int q = lane; q < ND; q += 64) acc += dq[q] * K2[o * ND + q];
    acc = wave_sum(acc);
    if (lane == 0) F[OF_r + 16 + o] = ok ? acc : 0.f;
  } else {
    for (int q = lane; q < ND; q += 64) acc += dq[q] * dk[q];
    acc = wave_sum(acc);
    if (lane == 0) F[OF_w + 16] = acc;
  }
}

__global__ void k_multi(const float* __restrict__ a, const float* __restrict__ bb,
                        const float* __restrict__ bc, float* __restrict__ out)
{
  int i = blockIdx.x * blockDim.x + threadIdx.x;
  if (i >= NB * NM * NM * 2) return;
  int c = i & 1;
  int t = i >> 1;
  int n = t % NM; t /= NM;
  int m = t % NM;
  int b = t / NM;
  out[i] = a[((size_t)b * NM + m) * 2 + c] + bb[((size_t)b * NM + n) * 2 + c] + bc[c];
}

template <int O, int NVX>
static void run_rounds(hipStream_t stream,
                       float* keyb, float* valb,
                       const float* kmp, const float* vmp, int vmOff, int vmStride,
                       const float* Wb, const float* lwp, const float* lbp,
                       float* fold, float* linK, float* linV,
                       float* tmp, float* Y1, float* outp,
                       const float* typeSrc, const float* keyMaskG, float* km2G, int doType)
{
  dim3 blk(256);
  for (int r = 0; r < 5; ++r) {
    k_tmpM<<<dim3(10, O, NB), blk, 0, stream>>>(keyb, Wb, tmp, O,
        typeSrc, keyMaskG, km2G, (r == 0) ? doType : 0);
    if (r < 4) {
      k_bilatt0<O, NVX><<<dim3(NB * NM), blk, 0, stream>>>(
          tmp, valb, linK, linV, lbp, fold, kmp, vmp, vmOff, vmStride, Y1);
      k_updB<O, NVX><<<dim3(NB * (NVX + NM)), blk, 0, stream>>>(
          Y1, fold, kmp, vmp, vmOff, vmStride, keyb, valb, lwp, linK, linV);
    } else {
      k_bilfin<O, NVX><<<dim3(NB * NM), blk, 0, stream>>>(
          tmp, valb, linK, linV, lbp, kmp, vmp, vmOff, vmStride, outp);
    }
  }
}

extern "C" void kernel_launch(void* const* d_in, const int* in_sizes, int n_in,
                              void* d_out, int out_size, void* d_ws, size_t ws_size,
                              hipStream_t stream)
{
  const float* key        = (const float*)d_in[0];
  const float* value      = (const float*)d_in[1];
  const float* key_mask   = (const float*)d_in[2];
  const float* value_mask = (const float*)d_in[3];
  const float* w_kt = (const float*)d_in[4];  const float* b_kt = (const float*)d_in[5];
  const float* w_vt = (const float*)d_in[6];  const float* b_vt = (const float*)d_in[7];
  const float* w_km = (const float*)d_in[8];  const float* b_km = (const float*)d_in[9];
  const float* w_vm = (const float*)d_in[10]; const float* b_vm = (const float*)d_in[11];
  const float* w_ks = (const float*)d_in[12]; const float* b_ks = (const float*)d_in[13];
  const float* w_vs = (const float*)d_in[14]; const float* b_vs = (const float*)d_in[15];
  const float* bt_W = (const float*)d_in[16]; const float* bt_lw = (const float*)d_in[17];
  const float* bt_lb = (const float*)d_in[18];
  const float* bi_W = (const float*)d_in[19]; const float* bi_lw = (const float*)d_in[20];
  const float* bi_lb = (const float*)d_in[21];
  const float* w_ffnt = (const float*)d_in[22]; const float* b_ffnt = (const float*)d_in[23];
  const float* w_ffn  = (const float*)d_in[24]; const float* b_ffn  = (const float*)d_in[25];
  const float* qkvt_w = (const float*)d_in[26]; const float* qkvt_b = (const float*)d_in[27];
  const float* qkv_w  = (const float*)d_in[28]; const float* qkv_b  = (const float*)d_in[29];
  const float* w_cls  = (const float*)d_in[30]; const float* b_cls  = (const float*)d_in[31];

  float* ws = (float*)d_ws;
  size_t off = 0;
  auto alloc = [&](size_t nfloat) { float* p = ws + off; off += (nfloat + 3) & ~(size_t)3; return p; };

  float* kt_t   = alloc((size_t)NB * NM * ND);
  float* vt_t   = alloc((size_t)NB * NNV * ND);
  float* kt_s   = alloc((size_t)NB * NM * ND);
  float* vt_s   = alloc((size_t)NB * NM * ND);
  float* tmp    = alloc((size_t)NB * 3 * NM * ND);
  float* Y1     = alloc((size_t)NB * NM * NNV * 3);
  float* linK_t = alloc((size_t)NB * NM * 3);
  float* linV_t = alloc((size_t)NB * NNV * 3);
  float* linK_s = alloc((size_t)NB * NM * 3);
  float* linV_s = alloc((size_t)NB * NM * 3);
  float* fold_t = alloc(FOLD_SZ);
  float* fold_s = alloc(FOLD_SZ);
  float* km2    = alloc((size_t)NB * NM);
  float* a2     = alloc((size_t)NB * NM * 2);
  float* b2     = alloc((size_t)NB * NM * 2);
  (void)ws_size; (void)in_sizes; (void)n_in; (void)out_size;

  float* kmf = tmp;                               // projections done before rounds use tmp
  float* vmf = tmp + (size_t)NB * NM * ND;

  float* out_type   = (float*)d_out;
  float* out_multi  = out_type + (size_t)NB * NM * NNV * 3;
  float* out_single = out_multi + (size_t)NB * NM * NM * 2;

  dim3 blk(256);

  // ---- all 6 big projections, one MFMA launch ----
  Proj6 P;
  P.c[0] = { key,   w_kt, b_kt, kt_t, NB * NM,  0, NM,  NM * NH };
  P.c[1] = { value, w_vt, b_vt, vt_t, NB * NNV, 0, NNV, NNV * NH };
  P.c[2] = { key,   w_ks, b_ks, kt_s, NB * NM,  0, NM,  NM * NH };
  P.c[3] = { value, w_vs, b_vs, vt_s, NB * NM,  1, NM,  NNV * NH };
  P.c[4] = { key,   w_km, b_km, kmf,  NB * NM,  0, NM,  NM * NH };
  P.c[5] = { value, w_vm, b_vm, vmf,  NB * NM,  1, NM,  NNV * NH };
  k_projM<<<dim3(193 * 10), blk, 0, stream>>>(P, NH);

  // ---- folds for both paths (batched) ----
  FoldCfg ft = { w_ffnt, b_ffnt, qkvt_w, qkvt_b, fold_t, 3 };
  FoldCfg fs = { w_ffn,  b_ffn,  qkv_w,  qkv_b,  fold_s, 2 };
  k_fold1B<<<dim3(360, 2), blk, 0, stream>>>(ft, fs);
  k_fold2B<<<dim3(364, 2), blk, 0, stream>>>(ft, fs);
  k_fold3B<<<dim3(4, 2), blk, 0, stream>>>(ft, fs);

  // ---- all small matvecs, one launch ----
  SpCfg s0 = { kt_t, bt_lw, linK_t, NB * NM,  3, 2 * ND, 0 };
  SpCfg s1 = { vt_t, bt_lw, linV_t, NB * NNV, 3, 2 * ND, ND };
  SpCfg s2 = { kt_s, bi_lw, linK_s, NB * NM,  2, 2 * ND, 0 };
  SpCfg s3 = { vt_s, bi_lw, linV_s, NB * NM,  2, 2 * ND, ND };
  SpCfg s4 = { kmf,  w_cls, a2,     NB * NM,  2, 2 * ND, 0 };
  SpCfg s5 = { vmf,  w_cls, b2,     NB * NM,  2, 2 * ND, ND };
  k_sproj6<<<dim3((NB * NNV * 3 + 3) / 4, 6), blk, 0, stream>>>(s0, s1, s2, s3, s4, s5);

  // multi logits (independent of rounds)
  k_multi<<<dim3((NB * NM * NM * 2 + 255) / 256), blk, 0, stream>>>(a2, b2, b_cls, out_multi);

  // ---- type path rounds ----
  run_rounds<3, NNV>(stream, kt_t, vt_t, key_mask, value_mask, 0, NNV,
                     bt_W, bt_lw, bt_lb, fold_t, linK_t, linV_t,
                     tmp, Y1, out_type, nullptr, nullptr, nullptr, 0);

  // ---- single path rounds (first tmpM computes km2 from out_type in its epilogue) ----
  run_rounds<2, NM>(stream, kt_s, vt_s, km2, value_mask, 1, NNV,
                    bi_W, bi_lw, bi_lb, fold_s, linK_s, linV_s,
                    tmp, Y1, out_single, out_type, key_mask, km2, 1);
}

// Round 11
// 1072.370 us; speedup vs baseline: 3.8882x; 1.1862x over previous
//
#include <hip/hip_runtime.h>
#include <math.h>

// ---------------- problem constants ----------------
constexpr int NB = 32;    // B
constexpr int NM = 64;    // M
constexpr int NNV = 65;   // NV
constexpr int NH = 960;   // H
constexpr int ND = 480;   // D
constexpr float ATT_SCALE = 0.045643546458763842f;  // D^-0.5

constexpr int OF_Pq = 0;
constexpr int OF_cq = 4320;
constexpr int OF_Q2 = 5760;
constexpr int OF_V2 = OF_Q2 + 2*1440;
constexpr int OF_dq = 10080;
constexpr int OF_dv = OF_dq + 2*480;
constexpr int OF_S  = 11520;
constexpr int OF_u  = 11529;
constexpr int OF_r  = 11532;
constexpr int OF_w  = 11535;
constexpr int FOLD_SZ = 11552;

typedef unsigned short u16;
typedef float f32x4 __attribute__((ext_vector_type(4)));
typedef short s16x8 __attribute__((ext_vector_type(8)));

__device__ __forceinline__ float wave_sum(float v) {
#pragma unroll
  for (int d = 32; d; d >>= 1) v += __shfl_xor(v, d);
  return v;
}

__device__ __forceinline__ void split_bf16(float x, short& hi, short& lo) {
  union { float f; unsigned u; } a; a.f = x;
  unsigned uh = a.u + 0x7fffu + ((a.u >> 16) & 1u);
  hi = (short)(uh >> 16);
  union { unsigned u; float f; } b; b.u = ((unsigned)(unsigned short)hi) << 16;
  union { float f; unsigned u; } c; c.f = x - b.f;
  unsigned ul = c.u + 0x7fffu + ((c.u >> 16) & 1u);
  lo = (short)(ul >> 16);
}

// transpose-convert: dst[z][n][k] = split(src[z][k][n]) for 5 planes (bt_W 0..2, bi_W 0..1)
__global__ __launch_bounds__(256) void k_cvtT(
    const float* __restrict__ btW, const float* __restrict__ biW,
    u16* __restrict__ wtHi, u16* __restrict__ wtLo)
{
  __shared__ float s[32][33];
  const int z = blockIdx.z;
  const float* src = (z < 3) ? (btW + (size_t)z * ND * ND) : (biW + (size_t)(z - 3) * ND * ND);
  u16* dh = wtHi + (size_t)z * ND * ND;
  u16* dl = wtLo + (size_t)z * ND * ND;
  const int k0 = blockIdx.y * 32, n0 = blockIdx.x * 32;
  const int tx = threadIdx.x & 31, ty = threadIdx.x >> 5;
#pragma unroll
  for (int q = 0; q < 4; ++q)
    s[ty + q * 8][tx] = src[(size_t)(k0 + ty + q * 8) * ND + n0 + tx];
  __syncthreads();
#pragma unroll
  for (int q = 0; q < 4; ++q) {
    float v = s[tx][ty + q * 8];
    short h, l; split_bf16(v, h, l);
    size_t di = (size_t)(n0 + ty + q * 8) * ND + k0 + tx;
    dh[di] = (u16)h; dl[di] = (u16)l;
  }
}

// ---------------- MFMA split-bf16 projection GEMM (6 configs, XCD swizzled) ----------------
struct ProjCfg {
  const float* X; const float* W; const float* bias; float* C;
  int R; int x0; int rpb; int xbs;
};
struct Proj6 { ProjCfg c[6]; };

constexpr int KP = 40;   // padded k stride (ushorts)

__global__ __launch_bounds__(256) void k_projM(Proj6 P, int K)
{
  __shared__ u16 As_hi[64][KP], As_lo[64][KP];
  __shared__ u16 Bs_hi[48][KP], Bs_lo[48][KP];
  int p = blockIdx.x, total = gridDim.x;
  int q = total >> 3, r = total & 7;
  int xk = p & 7, idx = p >> 3;
  int lgc = (xk < r) ? (xk * (q + 1) + idx) : (r * (q + 1) + (xk - r) * q + idx);
  int mp = lgc / 10, nx = lgc - mp * 10;
  ProjCfg cfg; int my;
  if      (mp < 32)  { cfg = P.c[0]; my = mp; }
  else if (mp < 65)  { cfg = P.c[1]; my = mp - 32; }
  else if (mp < 97)  { cfg = P.c[2]; my = mp - 65; }
  else if (mp < 129) { cfg = P.c[3]; my = mp - 97; }
  else if (mp < 161) { cfg = P.c[4]; my = mp - 129; }
  else               { cfg = P.c[5]; my = mp - 161; }
  const int m0 = my * 64, n0 = nx * 48;
  const int tid = threadIdx.x;
  const int l6 = tid & 63, w = tid >> 6;
  const int lr = tid >> 2, kc = (tid & 3) * 8;
  const float* Arow = nullptr;
  {
    int rr = m0 + lr;
    if (rr < cfg.R) {
      int b = rr / cfg.rpb, r2 = rr - b * cfg.rpb;
      Arow = cfg.X + (size_t)b * cfg.xbs + (size_t)(cfg.x0 + r2) * K;
    }
  }
  const float* Brow = (lr < 48) ? (cfg.W + (size_t)(n0 + lr) * K) : nullptr;
  const int fr = l6 & 15, fk = (l6 >> 4) * 8;
  f32x4 acc0 = {0.f, 0.f, 0.f, 0.f}, acc1 = acc0, acc2 = acc0;
  for (int k0 = 0; k0 < K; k0 += 32) {
    float xs[8] = {0.f, 0.f, 0.f, 0.f, 0.f, 0.f, 0.f, 0.f};
    if (Arow) {
      float4 a0 = *(const float4*)(Arow + k0 + kc);
      float4 a1 = *(const float4*)(Arow + k0 + kc + 4);
      xs[0] = a0.x; xs[1] = a0.y; xs[2] = a0.z; xs[3] = a0.w;
      xs[4] = a1.x; xs[5] = a1.y; xs[6] = a1.z; xs[7] = a1.w;
    }
    s16x8 vh, vl;
#pragma unroll
    for (int e = 0; e < 8; ++e) { short h, lo2; split_bf16(xs[e], h, lo2); vh[e] = h; vl[e] = lo2; }
    *(s16x8*)&As_hi[lr][kc] = vh;
    *(s16x8*)&As_lo[lr][kc] = vl;
    if (Brow) {
      float4 b0 = *(const float4*)(Brow + k0 + kc);
      float4 b1 = *(const float4*)(Brow + k0 + kc + 4);
      float ys[8] = {b0.x, b0.y, b0.z, b0.w, b1.x, b1.y, b1.z, b1.w};
      s16x8 wh, wl;
#pragma unroll
      for (int e = 0; e < 8; ++e) { short h, lo2; split_bf16(ys[e], h, lo2); wh[e] = h; wl[e] = lo2; }
      *(s16x8*)&Bs_hi[lr][kc] = wh;
      *(s16x8*)&Bs_lo[lr][kc] = wl;
    }
    __syncthreads();
    s16x8 ah = *(const s16x8*)&As_hi[16 * w + fr][fk];
    s16x8 al = *(const s16x8*)&As_lo[16 * w + fr][fk];
    {
      s16x8 bh = *(const s16x8*)&Bs_hi[fr][fk];
      s16x8 bl = *(const s16x8*)&Bs_lo[fr][fk];
      acc0 = __builtin_amdgcn_mfma_f32_16x16x32_bf16(ah, bh, acc0, 0, 0, 0);
      acc0 = __builtin_amdgcn_mfma_f32_16x16x32_bf16(ah, bl, acc0, 0, 0, 0);
      acc0 = __builtin_amdgcn_mfma_f32_16x16x32_bf16(al, bh, acc0, 0, 0, 0);
    }
    {
      s16x8 bh = *(const s16x8*)&Bs_hi[16 + fr][fk];
      s16x8 bl = *(const s16x8*)&Bs_lo[16 + fr][fk];
      acc1 = __builtin_amdgcn_mfma_f32_16x16x32_bf16(ah, bh, acc1, 0, 0, 0);
      acc1 = __builtin_amdgcn_mfma_f32_16x16x32_bf16(ah, bl, acc1, 0, 0, 0);
      acc1 = __builtin_amdgcn_mfma_f32_16x16x32_bf16(al, bh, acc1, 0, 0, 0);
    }
    {
      s16x8 bh = *(const s16x8*)&Bs_hi[32 + fr][fk];
      s16x8 bl = *(const s16x8*)&Bs_lo[32 + fr][fk];
      acc2 = __builtin_amdgcn_mfma_f32_16x16x32_bf16(ah, bh, acc2, 0, 0, 0);
      acc2 = __builtin_amdgcn_mfma_f32_16x16x32_bf16(ah, bl, acc2, 0, 0, 0);
      acc2 = __builtin_amdgcn_mfma_f32_16x16x32_bf16(al, bh, acc2, 0, 0, 0);
    }
    __syncthreads();
  }
#pragma unroll
  for (int c = 0; c < 3; ++c) {
    f32x4 av = (c == 0) ? acc0 : (c == 1) ? acc1 : acc2;
    int n = n0 + 16 * c + fr;
    float bv = cfg.bias[n];
#pragma unroll
    for (int g = 0; g < 4; ++g) {
      int rr = m0 + 16 * w + (l6 >> 4) * 4 + g;
      if (rr < cfg.R) cfg.C[(size_t)rr * ND + n] = av[g] + bv;
    }
  }
}

// ---------------- MFMA tmp GEMM: on-fly A (fp32 key), plane-based B (W^T u16) ----------------
__global__ __launch_bounds__(256) void k_tmpM(
    const float* __restrict__ Key,
    const u16* __restrict__ WtH, const u16* __restrict__ WtL,
    float* __restrict__ T, int O,
    const float* __restrict__ typeSrc, const float* __restrict__ keyMask,
    float* __restrict__ km2, int doType)
{
  __shared__ u16 As_hi[64][KP], As_lo[64][KP];
  __shared__ u16 Bs_hi[48][KP], Bs_lo[48][KP];
  const int n0 = blockIdx.x * 48;
  const int o = blockIdx.y, b = blockIdx.z;
  const int tid = threadIdx.x;
  if (doType && blockIdx.x == 0 && blockIdx.y == 0 && tid < NM) {
    const float* p = typeSrc + ((size_t)(b * NM + tid)) * NNV * 3;
    float l0 = p[0], l1 = p[1], l2 = p[2];
    int arg = 0; float best = l0;
    if (l1 > best) { best = l1; arg = 1; }
    if (l2 > best) { arg = 2; }
    km2[b * NM + tid] = (keyMask[b * NM + tid] != 0.f && arg == 1) ? 1.f : 0.f;
  }
  const int l6 = tid & 63, w = tid >> 6;
  const int lr = tid >> 2, kc = (tid & 3) * 8;
  const float* Arow = Key + (size_t)b * NM * ND + (size_t)lr * ND;
  const bool bok = lr < 48;
  const size_t boff = ((size_t)o * ND + n0 + (bok ? lr : 0)) * ND;
  const int fr = l6 & 15, fk = (l6 >> 4) * 8;
  f32x4 acc0 = {0.f, 0.f, 0.f, 0.f}, acc1 = acc0, acc2 = acc0;
  for (int k0 = 0; k0 < ND; k0 += 32) {
    {
      float4 a0 = *(const float4*)(Arow + k0 + kc);
      float4 a1 = *(const float4*)(Arow + k0 + kc + 4);
      float xs[8] = {a0.x, a0.y, a0.z, a0.w, a1.x, a1.y, a1.z, a1.w};
      s16x8 vh, vl;
#pragma unroll
      for (int e = 0; e < 8; ++e) { short h, lo2; split_bf16(xs[e], h, lo2); vh[e] = h; vl[e] = lo2; }
      *(s16x8*)&As_hi[lr][kc] = vh;
      *(s16x8*)&As_lo[lr][kc] = vl;
    }
    if (bok) {
      *(s16x8*)&Bs_hi[lr][kc] = *(const s16x8*)(WtH + boff + k0 + kc);
      *(s16x8*)&Bs_lo[lr][kc] = *(const s16x8*)(WtL + boff + k0 + kc);
    }
    __syncthreads();
    s16x8 ah = *(const s16x8*)&As_hi[16 * w + fr][fk];
    s16x8 al = *(const s16x8*)&As_lo[16 * w + fr][fk];
    {
      s16x8 bh = *(const s16x8*)&Bs_hi[fr][fk];
      s16x8 bl = *(const s16x8*)&Bs_lo[fr][fk];
      acc0 = __builtin_amdgcn_mfma_f32_16x16x32_bf16(ah, bh, acc0, 0, 0, 0);
      acc0 = __builtin_amdgcn_mfma_f32_16x16x32_bf16(ah, bl, acc0, 0, 0, 0);
      acc0 = __builtin_amdgcn_mfma_f32_16x16x32_bf16(al, bh, acc0, 0, 0, 0);
    }
    {
      s16x8 bh = *(const s16x8*)&Bs_hi[16 + fr][fk];
      s16x8 bl = *(const s16x8*)&Bs_lo[16 + fr][fk];
      acc1 = __builtin_amdgcn_mfma_f32_16x16x32_bf16(ah, bh, acc1, 0, 0, 0);
      acc1 = __builtin_amdgcn_mfma_f32_16x16x32_bf16(ah, bl, acc1, 0, 0, 0);
      acc1 = __builtin_amdgcn_mfma_f32_16x16x32_bf16(al, bh, acc1, 0, 0, 0);
    }
    {
      s16x8 bh = *(const s16x8*)&Bs_hi[32 + fr][fk];
      s16x8 bl = *(const s16x8*)&Bs_lo[32 + fr][fk];
      acc2 = __builtin_amdgcn_mfma_f32_16x16x32_bf16(ah, bh, acc2, 0, 0, 0);
      acc2 = __builtin_amdgcn_mfma_f32_16x16x32_bf16(ah, bl, acc2, 0, 0, 0);
      acc2 = __builtin_amdgcn_mfma_f32_16x16x32_bf16(al, bh, acc2, 0, 0, 0);
    }
    __syncthreads();
  }
  float* C = T + ((size_t)(b * O + o) * NM) * ND;
#pragma unroll
  for (int c = 0; c < 3; ++c) {
    f32x4 av = (c == 0) ? acc0 : (c == 1) ? acc1 : acc2;
    int n = n0 + 16 * c + fr;
#pragma unroll
    for (int g = 0; g < 4; ++g) {
      int rr = 16 * w + (l6 >> 4) * 4 + g;
      C[(size_t)rr * ND + n] = av[g];
    }
  }
}

// fused bilinear + attention(MODE0) per (b,m) with parallel softmax
template <int O, int NVX>
__global__ __launch_bounds__(256) void k_bilatt0(
    const float* __restrict__ T, const float* __restrict__ Val,
    const float* __restrict__ linK, const float* __restrict__ linV,
    const float* __restrict__ lb, const float* __restrict__ F,
    const float* __restrict__ km, const float* __restrict__ vm,
    int vmOff, int vmStride, float* __restrict__ Y1)
{
  __shared__ float Ls[NVX][3];
  __shared__ float STs[NVX][3];
  __shared__ float hs[NVX], gs[NVX], mkj[NVX];
  __shared__ float Pm[NVX][66];
  __shared__ float rmx[NVX][3];
  __shared__ float rsum[NVX][3];
  __shared__ float ry[NVX][3][3];
  __shared__ float lvs[NVX][3];
  const int b = blockIdx.x >> 6, m = blockIdx.x & 63;
  const int tid = threadIdx.x;
  const int lane = tid & 63, w = tid >> 6;

  for (int j = tid; j < NVX; j += 256) {
    mkj[j] = vm[b * vmStride + vmOff + j];
#pragma unroll
    for (int o = 0; o < O; ++o) lvs[j][o] = linV[((size_t)b * NVX + j) * O + o];
  }
  float4 tsr[O][2];
#pragma unroll
  for (int o = 0; o < O; ++o) {
    const float4* trow = (const float4*)(T + (((size_t)b * O + o) * NM + m) * (size_t)ND);
    tsr[o][0] = trow[lane];
    tsr[o][1] = (lane < 56) ? trow[64 + lane] : make_float4(0.f, 0.f, 0.f, 0.f);
  }
  float lk[O];
#pragma unroll
  for (int o = 0; o < O; ++o) lk[o] = linK[((size_t)b * NM + m) * O + o] + lb[o];
  const float gm = km[b * NM + m];
  const bool gz = (gm == 0.f);

  for (int n = w; n < NVX; n += 4) {
    const float4* vrow = (const float4*)(Val + ((size_t)b * NVX + n) * (size_t)ND);
    float4 v0 = vrow[lane];
    float4 v1 = (lane < 56) ? vrow[64 + lane] : make_float4(0.f, 0.f, 0.f, 0.f);
    float a[3] = {0.f, 0.f, 0.f};
#pragma unroll
    for (int o = 0; o < O; ++o) {
      a[o] = v0.x * tsr[o][0].x + v0.y * tsr[o][0].y + v0.z * tsr[o][0].z + v0.w * tsr[o][0].w
           + v1.x * tsr[o][1].x + v1.y * tsr[o][1].y + v1.z * tsr[o][1].z + v1.w * tsr[o][1].w;
    }
#pragma unroll
    for (int o = 0; o < O; ++o) a[o] = wave_sum(a[o]);
    if (lane == 0) {
#pragma unroll
      for (int o = 0; o < O; ++o) Ls[n][o] = a[o] + lk[o] + lvs[n][o];
      if (O == 2) Ls[n][2] = 0.f;
    }
  }
  __syncthreads();
  const float* Sm = F + OF_S;
  const float u0 = F[OF_u], u1 = F[OF_u + 1], u2 = F[OF_u + 2];
  const float r0 = F[OF_r], r1 = F[OF_r + 1], r2 = F[OF_r + 2];
  const float wc = F[OF_w];
  if (tid < NVX) {
    int j = tid;
    float t0 = Ls[j][0], t1 = Ls[j][1], t2 = Ls[j][2];
    STs[j][0] = t0 * Sm[0] + t1 * Sm[3] + t2 * Sm[6];
    STs[j][1] = t0 * Sm[1] + t1 * Sm[4] + t2 * Sm[7];
    STs[j][2] = t0 * Sm[2] + t1 * Sm[5] + t2 * Sm[8];
    hs[j] = t0 * u0 + t1 * u1 + t2 * u2;
    gs[j] = t0 * r0 + t1 * r1 + t2 * r2;
  }
  __syncthreads();
  const bool act = tid < NVX * 3;
  int i = 0, qq = 0, jlo = 0, jhi = 0;
  float st0 = 0, st1 = 0, st2 = 0, hi = 0;
  bool rowz = true;
  if (act) {
    i = tid / 3; qq = tid - i * 3;
    jlo = qq * 22; jhi = (jlo + 22 < NVX) ? jlo + 22 : NVX;
    st0 = STs[i][0]; st1 = STs[i][1]; st2 = STs[i][2]; hi = hs[i];
    rowz = gz || (mkj[i] == 0.f);
    float mx = -3.0e38f;
    for (int j = jlo; j < jhi; ++j) {
      float s = st0 * Ls[j][0] + st1 * Ls[j][1] + hi + gs[j] + wc;
      if (O == 3) s += st2 * Ls[j][2];
      s = (rowz || mkj[j] == 0.f) ? -10000.f : ATT_SCALE * s;
      Pm[i][j] = s;
      mx = fmaxf(mx, s);
    }
    rmx[i][qq] = mx;
  }
  __syncthreads();
  if (act) {
    float mx = fmaxf(fmaxf(rmx[i][0], rmx[i][1]), rmx[i][2]);
    float sum = 0.f, y0 = 0.f, y1 = 0.f, y2 = 0.f;
    for (int j = jlo; j < jhi; ++j) {
      float pp = __expf(Pm[i][j] - mx);
      sum += pp; y0 += pp * Ls[j][0]; y1 += pp * Ls[j][1];
      if (O == 3) y2 += pp * Ls[j][2];
    }
    rsum[i][qq] = sum; ry[i][qq][0] = y0; ry[i][qq][1] = y1; ry[i][qq][2] = y2;
  }
  __syncthreads();
  if (tid < NVX) {
    int ii = tid;
    float sum = rsum[ii][0] + rsum[ii][1] + rsum[ii][2];
    float y0 = ry[ii][0][0] + ry[ii][1][0] + ry[ii][2][0];
    float y1 = ry[ii][0][1] + ry[ii][1][1] + ry[ii][2][1];
    float y2 = ry[ii][0][2] + ry[ii][1][2] + ry[ii][2][2];
    float inv = 1.f / sum;
    size_t ob = (((size_t)b * NM + m) * NVX + ii) * O;
    Y1[ob + 0] = y0 * inv;
    Y1[ob + 1] = y1 * inv;
    if (O == 3) Y1[ob + 2] = y2 * inv;
  }
}

// fused attention(MODE1) + value-update + linV per (b,n), parallel softmax
template <int O, int NVX>
__global__ __launch_bounds__(256) void k_att1vupd(
    const float* __restrict__ Y1, float* __restrict__ Y2,
    const float* __restrict__ F,
    const float* __restrict__ km, const float* __restrict__ vm,
    int vmOff, int vmStride,
    float* __restrict__ valb, const float* __restrict__ lw,
    float* __restrict__ linV)
{
  __shared__ float Ys1[NM][3];
  __shared__ float STs[NM][3];
  __shared__ float hs[NM], gs[NM], mkm[NM];
  __shared__ float Pm[NM][66];
  __shared__ float rmx[NM][3];
  __shared__ float rsum[NM][3];
  __shared__ float ry[NM][3][3];
  __shared__ float Ys2[NM][3];
  __shared__ float vrow[ND];
  const int b = blockIdx.x / NVX, n = blockIdx.x - b * NVX;
  const int tid = threadIdx.x;
  for (int u = tid; u < NM * O; u += 256) {
    int mm = u % NM, o = u / NM;
    Ys1[mm][o] = Y1[(((size_t)b * NM + mm) * NVX + n) * O + o];
  }
  if (tid < NM) {
    mkm[tid] = km[b * NM + tid];
    if (O == 2) Ys1[tid][2] = 0.f;
  }
  const float gm = vm[b * vmStride + vmOff + n];
  const bool gz = (gm == 0.f);
  __syncthreads();
  const float* Sm = F + OF_S + 16;
  const float u0 = F[OF_u + 16], u1 = F[OF_u + 17], u2 = F[OF_u + 18];
  const float r0 = F[OF_r + 16], r1 = F[OF_r + 17], r2 = F[OF_r + 18];
  const float wc = F[OF_w + 16];
  if (tid < NM) {
    int j = tid;
    float t0 = Ys1[j][0], t1 = Ys1[j][1], t2 = Ys1[j][2];
    STs[j][0] = t0 * Sm[0] + t1 * Sm[3] + t2 * Sm[6];
    STs[j][1] = t0 * Sm[1] + t1 * Sm[4] + t2 * Sm[7];
    STs[j][2] = t0 * Sm[2] + t1 * Sm[5] + t2 * Sm[8];
    hs[j] = t0 * u0 + t1 * u1 + t2 * u2;
    gs[j] = t0 * r0 + t1 * r1 + t2 * r2;
  }
  __syncthreads();
  const bool act = tid < NM * 3;
  int i = 0, qq = 0, jlo = 0, jhi = 0;
  float st0 = 0, st1 = 0, st2 = 0, hi = 0;
  bool rowz = true;
  if (act) {
    i = tid / 3; qq = tid - i * 3;
    jlo = qq * 22; jhi = (jlo + 22 < NM) ? jlo + 22 : NM;
    st0 = STs[i][0]; st1 = STs[i][1]; st2 = STs[i][2]; hi = hs[i];
    rowz = gz || (mkm[i] == 0.f);
    float mx = -3.0e38f;
    for (int j = jlo; j < jhi; ++j) {
      float s = st0 * Ys1[j][0] + st1 * Ys1[j][1] + hi + gs[j] + wc;
      if (O == 3) s += st2 * Ys1[j][2];
      s = (rowz || mkm[j] == 0.f) ? -10000.f : ATT_SCALE * s;
      Pm[i][j] = s;
      mx = fmaxf(mx, s);
    }
    rmx[i][qq] = mx;
  }
  __syncthreads();
  if (act) {
    float mx = fmaxf(fmaxf(rmx[i][0], rmx[i][1]), rmx[i][2]);
    float sum = 0.f, y0 = 0.f, y1 = 0.f, y2 = 0.f;
    for (int j = jlo; j < jhi; ++j) {
      float pp = __expf(Pm[i][j] - mx);
      sum += pp; y0 += pp * Ys1[j][0]; y1 += pp * Ys1[j][1];
      if (O == 3) y2 += pp * Ys1[j][2];
    }
    rsum[i][qq] = sum; ry[i][qq][0] = y0; ry[i][qq][1] = y1; ry[i][qq][2] = y2;
  }
  __syncthreads();
  if (tid < NM) {
    int ii = tid;
    float sum = rsum[ii][0] + rsum[ii][1] + rsum[ii][2];
    float y0 = ry[ii][0][0] + ry[ii][1][0] + ry[ii][2][0];
    float y1 = ry[ii][0][1] + ry[ii][1][1] + ry[ii][2][1];
    float y2 = ry[ii][0][2] + ry[ii][1][2] + ry[ii][2][2];
    float inv = 1.f / sum;
    y0 *= inv; y1 *= inv; y2 *= inv;
    size_t ob = (((size_t)b * NVX + n) * NM + ii) * O;
    Y2[ob + 0] = y0; Y2[ob + 1] = y1;
    if (O == 3) Y2[ob + 2] = y2;
    Ys2[ii][0] = y0; Ys2[ii][1] = y1; Ys2[ii][2] = (O == 3) ? y2 : 0.f;
  }
  __syncthreads();
  const float* V2 = F + OF_V2;
  const float* dv = F + OF_dv;
  for (int d = tid; d < ND; d += 256) {
    float v0 = V2[d], v1 = V2[ND + d], v2 = (O == 3) ? V2[2 * ND + d] : 0.f;
    float mx = -3.0e38f;
    for (int j = 0; j < NM; ++j) {
      float s = Ys2[j][0] * v0 + Ys2[j][1] * v1;
      if (O == 3) s += Ys2[j][2] * v2;
      mx = fmaxf(mx, s);
    }
    size_t di = ((size_t)b * NVX + n) * ND + d;
    float nv = valb[di] + mx + dv[d];
    valb[di] = nv;
    vrow[d] = nv;
  }
  __syncthreads();
  const int wv = tid >> 6, lane = tid & 63;
  if (wv < O) {
    float acc = 0.f;
    for (int d = lane; d < ND; d += 64) acc += vrow[d] * lw[(size_t)wv * 2 * ND + ND + d];
    acc = wave_sum(acc);
    if (lane == 0) linV[((size_t)b * NVX + n) * O + wv] = acc;
  }
}

// fused key-update + linK per (b,m)
template <int O, int NVX>
__global__ __launch_bounds__(256) void k_kupd(
    const float* __restrict__ Y2, const float* __restrict__ F,
    float* __restrict__ keyb, const float* __restrict__ lw,
    float* __restrict__ linK)
{
  __shared__ float Ys[NVX][3];
  __shared__ float krow[ND];
  const int b = blockIdx.x >> 6, m = blockIdx.x & 63;
  const int tid = threadIdx.x;
  for (int u = tid; u < NVX * O; u += 256) {
    int j = u % NVX, o = u / NVX;
    Ys[j][o] = Y2[(((size_t)b * NVX + j) * NM + m) * O + o];
  }
  __syncthreads();
  const float* V2 = F + OF_V2;
  const float* dv = F + OF_dv;
  for (int d = tid; d < ND; d += 256) {
    float v0 = V2[d], v1 = V2[ND + d], v2 = (O == 3) ? V2[2 * ND + d] : 0.f;
    float mx = -3.0e38f;
    for (int j = 0; j < NVX; ++j) {
      float s = Ys[j][0] * v0 + Ys[j][1] * v1;
      if (O == 3) s += Ys[j][2] * v2;
      mx = fmaxf(mx, s);
    }
    size_t di = ((size_t)b * NM + m) * ND + d;
    float nv = keyb[di] + mx + dv[d];
    keyb[di] = nv;
    krow[d] = nv;
  }
  __syncthreads();
  const int wv = tid >> 6, lane = tid & 63;
  if (wv < O) {
    float acc = 0.f;
    for (int d = lane; d < ND; d += 64) acc += krow[d] * lw[(size_t)wv * 2 * ND + d];
    acc = wave_sum(acc);
    if (lane == 0) linK[((size_t)b * NM + m) * O + wv] = acc;
  }
}

// final bilinear with mask, register-ts + global Val
template <int O, int NVX>
__global__ __launch_bounds__(256) void k_bilfin(
    const float* __restrict__ T, const float* __restrict__ Val,
    const float* __restrict__ linK, const float* __restrict__ linV,
    const float* __restrict__ lb, const float* __restrict__ km,
    const float* __restrict__ vm, int vmOff, int vmStride,
    float* __restrict__ Out)
{
  const int b = blockIdx.x >> 6, m = blockIdx.x & 63;
  const int tid = threadIdx.x;
  const int lane = tid & 63, w = tid >> 6;
  float4 tsr[O][2];
#pragma unroll
  for (int o = 0; o < O; ++o) {
    const float4* trow = (const float4*)(T + (((size_t)b * O + o) * NM + m) * (size_t)ND);
    tsr[o][0] = trow[lane];
    tsr[o][1] = (lane < 56) ? trow[64 + lane] : make_float4(0.f, 0.f, 0.f, 0.f);
  }
  float lk[O];
#pragma unroll
  for (int o = 0; o < O; ++o) lk[o] = linK[((size_t)b * NM + m) * O + o] + lb[o];
  const float kmv = km[b * NM + m];
  for (int n = w; n < NVX; n += 4) {
    const float4* vrow = (const float4*)(Val + ((size_t)b * NVX + n) * (size_t)ND);
    float4 v0 = vrow[lane];
    float4 v1 = (lane < 56) ? vrow[64 + lane] : make_float4(0.f, 0.f, 0.f, 0.f);
    float a[3] = {0.f, 0.f, 0.f};
#pragma unroll
    for (int o = 0; o < O; ++o) {
      a[o] = v0.x * tsr[o][0].x + v0.y * tsr[o][0].y + v0.z * tsr[o][0].z + v0.w * tsr[o][0].w
           + v1.x * tsr[o][1].x + v1.y * tsr[o][1].y + v1.z * tsr[o][1].z + v1.w * tsr[o][1].w;
    }
#pragma unroll
    for (int o = 0; o < O; ++o) a[o] = wave_sum(a[o]);
    if (lane == 0) {
      float msk = kmv * vm[b * vmStride + vmOff + n];
      size_t ob = (((size_t)b * NM + m) * NVX + n) * O;
#pragma unroll
      for (int o = 0; o < O; ++o)
        Out[ob + o] = (a[o] + lk[o] + linV[((size_t)b * NVX + n) * O + o]) * msk;
    }
  }
}

// batched small matvec
struct SpCfg { const float* X; const float* W; float* Out; int R; int O; int wStride; int wOff; };
__global__ __launch_bounds__(256) void k_sproj6(
    SpCfg s0, SpCfg s1, SpCfg s2, SpCfg s3, SpCfg s4, SpCfg s5)
{
  int z = blockIdx.y;
  SpCfg c = (z == 0) ? s0 : (z == 1) ? s1 : (z == 2) ? s2 : (z == 3) ? s3 : (z == 4) ? s4 : s5;
  int gid = blockIdx.x * 4 + (threadIdx.x >> 6);
  if (gid >= c.R * c.O) return;
  int lane = threadIdx.x & 63;
  int r = gid / c.O, o = gid - r * c.O;
  const float* x = c.X + (size_t)r * ND;
  const float* wp = c.W + (size_t)o * c.wStride + c.wOff;
  float acc = 0.f;
  for (int d = lane; d < ND; d += 64) acc += x[d] * wp[d];
  acc = wave_sum(acc);
  if (lane == 0) c.Out[gid] = acc;
}

// ---------------- folds ----------------
struct FoldCfg { const float* fw; const float* fb; const float* qw; const float* qb; float* F; int O; };

__global__ __launch_bounds__(256) void k_fold1B(FoldCfg A, FoldCfg Bc)
{
  FoldCfg c = (blockIdx.y == 0) ? A : Bc;
  int O = c.O;
  int gid = blockIdx.x * 4 + (threadIdx.x >> 6);
  int lane = threadIdx.x & 63;
  if (gid >= 3 * ND) return;
  int part = gid / ND, cc0 = gid - part * ND;
  const float* qrow = c.qw + (size_t)(part * ND + cc0) * ND;
  float p0 = 0.f, p1 = 0.f, p2 = 0.f, cc = 0.f;
  for (int d = lane; d < ND; d += 64) {
    float q = qrow[d];
    p0 += c.fw[d * O + 0] * q;
    p1 += c.fw[d * O + 1] * q;
    if (O == 3) p2 += c.fw[d * O + 2] * q;
    cc += c.fb[d] * q;
  }
  p0 = wave_sum(p0); p1 = wave_sum(p1); p2 = wave_sum(p2); cc = wave_sum(cc);
  if (lane == 0) {
    c.F[OF_Pq + part * 1440 + 0 * ND + cc0] = p0;
    c.F[OF_Pq + part * 1440 + 1 * ND + cc0] = p1;
    c.F[OF_Pq + part * 1440 + 2 * ND + cc0] = (O == 3) ? p2 : 0.f;
    c.F[OF_cq + part * ND + cc0] = cc + c.qb[part * ND + cc0];
  }
}

__global__ __launch_bounds__(256) void k_fold2B(FoldCfg A, FoldCfg Bc)
{
  FoldCfg c = (blockIdx.y == 0) ? A : Bc;
  int O = c.O;
  float* F = c.F;
  int gid = blockIdx.x * 4 + (threadIdx.x >> 6);
  int lane = threadIdx.x & 63;
  if (gid < 3 * ND) {
    int part = gid / ND, cc0 = gid - part * ND;
    const float* qrow = c.qw + (size_t)(part * ND + cc0) * ND;
    const float* Pv = F + OF_Pq + 2 * 1440;
    const float* cv = F + OF_cq + 2 * ND;
    float p0 = 0.f, p1 = 0.f, p2 = 0.f, cc = 0.f;
    for (int d = lane; d < ND; d += 64) {
      float q = qrow[d];
      p0 += Pv[0 * ND + d] * q;
      p1 += Pv[1 * ND + d] * q;
      if (O == 3) p2 += Pv[2 * ND + d] * q;
      cc += cv[d] * q;
    }
    p0 = wave_sum(p0); p1 = wave_sum(p1); p2 = wave_sum(p2); cc = wave_sum(cc);
    if (lane == 0) {
      F[OF_Q2 + part * 1440 + 0 * ND + cc0] = p0;
      F[OF_Q2 + part * 1440 + 1 * ND + cc0] = p1;
      F[OF_Q2 + part * 1440 + 2 * ND + cc0] = (O == 3) ? p2 : 0.f;
      F[OF_dq + part * ND + cc0] = cc + c.qb[part * ND + cc0];
    }
  } else if (gid < 3 * ND + 16) {
    int s = gid - 3 * ND;
    const float* Pq = F + OF_Pq;
    const float* Pk = F + OF_Pq + 1440;
    const float* cq = F + OF_cq;
    const float* ck = F + OF_cq + ND;
    float acc = 0.f;
    if (s < 9) {
      int o = s / 3, op = s % 3;
      bool ok = (o < O) && (op < O);
      if (ok) for (int q = lane; q < ND; q += 64) acc += Pq[o * ND + q] * Pk[op * ND + q];
      acc = wave_sum(acc);
      if (lane == 0) F[OF_S + s] = ok ? acc : 0.f;
    } else if (s < 12) {
      int o = s - 9; bool ok = o < O;
      if (ok) for (int q = lane; q < ND; q += 64) acc += Pq[o * ND + q] * ck[q];
      acc = wave_sum(acc);
      if (lane == 0) F[OF_u + o] = ok ? acc : 0.f;
    } else if (s < 15) {
      int o = s - 12; bool ok = o < O;
      if (ok) for (int q = lane; q < ND; q += 64) acc += cq[q] * Pk[o * ND + q];
      acc = wave_sum(acc);
      if (lane == 0) F[OF_r + o] = ok ? acc : 0.f;
    } else {
      for (int q = lane; q < ND; q += 64) acc += cq[q] * ck[q];
      acc = wave_sum(acc);
      if (lane == 0) F[OF_w] = acc;
    }
  }
}

__global__ __launch_bounds__(256) void k_fold3B(FoldCfg A, FoldCfg Bc)
{
  FoldCfg c = (blockIdx.y == 0) ? A : Bc;
  int O = c.O;
  float* F = c.F;
  int s = blockIdx.x * 4 + (threadIdx.x >> 6);
  int lane = threadIdx.x & 63;
  if (s >= 16) return;
  const float* Q2 = F + OF_Q2;
  const float* K2 = F + OF_Q2 + 1440;
  const float* dq = F + OF_dq;
  const float* dk = F + OF_dq + ND;
  float acc = 0.f;
  if (s < 9) {
    int o = s / 3, op = s % 3;
    bool ok = (o < O) && (op < O);
    if (ok) for (int q = lane; q < ND; q += 64) acc += Q2[o * ND + q] * K2[op * ND + q];
    acc = wave_sum(acc);
    if (lane == 0) F[OF_S + 16 + s] = ok ? acc : 0.f;
  } else if (s < 12) {
    int o = s - 9; bool ok = o < O;
    if (ok) for (int q = lane; q < ND; q += 64) acc += Q2[o * ND + q] * dk[q];
    acc = wave_sum(acc);
    if (lane == 0) F[OF_u + 16 + o] = ok ? acc : 0.f;
  } else if (s < 15) {
    int o = s - 12; bool ok = o < O;
    if (ok) for (int q = lane; q < ND; q += 64) acc += dq[q] * K2[o * ND + q];
    acc = wave_sum(acc);
    if (lane == 0) F[OF_r + 16 + o] = ok ? acc : 0.f;
  } else {
    for (int q = lane; q < ND; q += 64) acc += dq[q] * dk[q];
    acc = wave_sum(acc);
    if (lane == 0) F[OF_w + 16] = acc;
  }
}

__global__ void k_multi(const float* __restrict__ a, const float* __restrict__ bb,
                        const float* __restrict__ bc, float* __restrict__ out)
{
  int i = blockIdx.x * blockDim.x + threadIdx.x;
  if (i >= NB * NM * NM * 2) return;
  int c = i & 1;
  int t = i >> 1;
  int n = t % NM; t /= NM;
  int m = t % NM;
  int b = t / NM;
  out[i] = a[((size_t)b * NM + m) * 2 + c] + bb[((size_t)b * NM + n) * 2 + c] + bc[c];
}

template <int O, int NVX>
static void run_rounds(hipStream_t stream,
                       float* keyb, float* valb,
                       const float* kmp, const float* vmp, int vmOff, int vmStride,
                       const u16* WtHp, const u16* WtLp,
                       const float* lwp, const float* lbp,
                       float* fold, float* linK, float* linV,
                       float* tmp, float* Y1, float* Y2, float* outp,
                       const float* typeSrc, const float* keyMaskG, float* km2G, int doType)
{
  dim3 blk(256);
  for (int r = 0; r < 5; ++r) {
    k_tmpM<<<dim3(10, O, NB), blk, 0, stream>>>(keyb, WtHp, WtLp, tmp, O,
        typeSrc, keyMaskG, km2G, (r == 0) ? doType : 0);
    if (r < 4) {
      k_bilatt0<O, NVX><<<dim3(NB * NM), blk, 0, stream>>>(
          tmp, valb, linK, linV, lbp, fold, kmp, vmp, vmOff, vmStride, Y1);
      k_att1vupd<O, NVX><<<dim3(NB * NVX), blk, 0, stream>>>(
          Y1, Y2, fold, kmp, vmp, vmOff, vmStride, valb, lwp, linV);
      k_kupd<O, NVX><<<dim3(NB * NM), blk, 0, stream>>>(Y2, fold, keyb, lwp, linK);
    } else {
      k_bilfin<O, NVX><<<dim3(NB * NM), blk, 0, stream>>>(
          tmp, valb, linK, linV, lbp, kmp, vmp, vmOff, vmStride, outp);
    }
  }
}

extern "C" void kernel_launch(void* const* d_in, const int* in_sizes, int n_in,
                              void* d_out, int out_size, void* d_ws, size_t ws_size,
                              hipStream_t stream)
{
  const float* key        = (const float*)d_in[0];
  const float* value      = (const float*)d_in[1];
  const float* key_mask   = (const float*)d_in[2];
  const float* value_mask = (const float*)d_in[3];
  const float* w_kt = (const float*)d_in[4];  const float* b_kt = (const float*)d_in[5];
  const float* w_vt = (const float*)d_in[6];  const float* b_vt = (const float*)d_in[7];
  const float* w_km = (const float*)d_in[8];  const float* b_km = (const float*)d_in[9];
  const float* w_vm = (const float*)d_in[10]; const float* b_vm = (const float*)d_in[11];
  const float* w_ks = (const float*)d_in[12]; const float* b_ks = (const float*)d_in[13];
  const float* w_vs = (const float*)d_in[14]; const float* b_vs = (const float*)d_in[15];
  const float* bt_W = (const float*)d_in[16]; const float* bt_lw = (const float*)d_in[17];
  const float* bt_lb = (const float*)d_in[18];
  const float* bi_W = (const float*)d_in[19]; const float* bi_lw = (const float*)d_in[20];
  const float* bi_lb = (const float*)d_in[21];
  const float* w_ffnt = (const float*)d_in[22]; const float* b_ffnt = (const float*)d_in[23];
  const float* w_ffn  = (const float*)d_in[24]; const float* b_ffn  = (const float*)d_in[25];
  const float* qkvt_w = (const float*)d_in[26]; const float* qkvt_b = (const float*)d_in[27];
  const float* qkv_w  = (const float*)d_in[28]; const float* qkv_b  = (const float*)d_in[29];
  const float* w_cls  = (const float*)d_in[30]; const float* b_cls  = (const float*)d_in[31];

  float* ws = (float*)d_ws;
  size_t off = 0;
  auto alloc = [&](size_t nfloat) { float* p = ws + off; off += (nfloat + 3) & ~(size_t)3; return p; };

  float* kt_t   = alloc((size_t)NB * NM * ND);
  float* vt_t   = alloc((size_t)NB * NNV * ND);
  float* kt_s   = alloc((size_t)NB * NM * ND);
  float* vt_s   = alloc((size_t)NB * NM * ND);
  float* tmp    = alloc((size_t)NB * 3 * NM * ND);
  float* Y1     = alloc((size_t)NB * NM * NNV * 3);
  float* Y2     = alloc((size_t)NB * NM * NNV * 3);
  float* linK_t = alloc((size_t)NB * NM * 3);
  float* linV_t = alloc((size_t)NB * NNV * 3);
  float* linK_s = alloc((size_t)NB * NM * 3);
  float* linV_s = alloc((size_t)NB * NM * 3);
  float* fold_t = alloc(FOLD_SZ);
  float* fold_s = alloc(FOLD_SZ);
  float* km2    = alloc((size_t)NB * NM);
  float* a2     = alloc((size_t)NB * NM * 2);
  float* b2     = alloc((size_t)NB * NM * 2);
  u16* WtH = (u16*)alloc((size_t)5 * ND * ND / 2);
  u16* WtL = (u16*)alloc((size_t)5 * ND * ND / 2);
  (void)ws_size; (void)in_sizes; (void)n_in; (void)out_size;

  float* kmf = tmp;                               // projections done before rounds use tmp
  float* vmf = tmp + (size_t)NB * NM * ND;

  float* out_type   = (float*)d_out;
  float* out_multi  = out_type + (size_t)NB * NM * NNV * 3;
  float* out_single = out_multi + (size_t)NB * NM * NM * 2;

  dim3 blk(256);

  // ---- W^T bf16 planes for the 5 biaffine matrices (one-time) ----
  k_cvtT<<<dim3(15, 15, 5), blk, 0, stream>>>(bt_W, bi_W, WtH, WtL);

  // ---- all 6 big projections, one MFMA launch ----
  Proj6 P;
  P.c[0] = { key,   w_kt, b_kt, kt_t, NB * NM,  0, NM,  NM * NH };
  P.c[1] = { value, w_vt, b_vt, vt_t, NB * NNV, 0, NNV, NNV * NH };
  P.c[2] = { key,   w_ks, b_ks, kt_s, NB * NM,  0, NM,  NM * NH };
  P.c[3] = { value, w_vs, b_vs, vt_s, NB * NM,  1, NM,  NNV * NH };
  P.c[4] = { key,   w_km, b_km, kmf,  NB * NM,  0, NM,  NM * NH };
  P.c[5] = { value, w_vm, b_vm, vmf,  NB * NM,  1, NM,  NNV * NH };
  k_projM<<<dim3(193 * 10), blk, 0, stream>>>(P, NH);

  // ---- folds for both paths (batched) ----
  FoldCfg ft = { w_ffnt, b_ffnt, qkvt_w, qkvt_b, fold_t, 3 };
  FoldCfg fs = { w_ffn,  b_ffn,  qkv_w,  qkv_b,  fold_s, 2 };
  k_fold1B<<<dim3(360, 2), blk, 0, stream>>>(ft, fs);
  k_fold2B<<<dim3(364, 2), blk, 0, stream>>>(ft, fs);
  k_fold3B<<<dim3(4, 2), blk, 0, stream>>>(ft, fs);

  // ---- all small matvecs, one launch ----
  SpCfg s0 = { kt_t, bt_lw, linK_t, NB * NM,  3, 2 * ND, 0 };
  SpCfg s1 = { vt_t, bt_lw, linV_t, NB * NNV, 3, 2 * ND, ND };
  SpCfg s2 = { kt_s, bi_lw, linK_s, NB * NM,  2, 2 * ND, 0 };
  SpCfg s3 = { vt_s, bi_lw, linV_s, NB * NM,  2, 2 * ND, ND };
  SpCfg s4 = { kmf,  w_cls, a2,     NB * NM,  2, 2 * ND, 0 };
  SpCfg s5 = { vmf,  w_cls, b2,     NB * NM,  2, 2 * ND, ND };
  k_sproj6<<<dim3((NB * NNV * 3 + 3) / 4, 6), blk, 0, stream>>>(s0, s1, s2, s3, s4, s5);

  // multi logits (independent of rounds)
  k_multi<<<dim3((NB * NM * NM * 2 + 255) / 256), blk, 0, stream>>>(a2, b2, b_cls, out_multi);

  // ---- type path rounds ----
  run_rounds<3, NNV>(stream, kt_t, vt_t, key_mask, value_mask, 0, NNV,
                     WtH, WtL, bt_lw, bt_lb, fold_t, linK_t, linV_t,
                     tmp, Y1, Y2, out_type, nullptr, nullptr, nullptr, 0);

  // ---- single path rounds (first tmpM computes km2 from out_type in its epilogue) ----
  run_rounds<2, NM>(stream, kt_s, vt_s, km2, value_mask, 1, NNV,
                    WtH + (size_t)3 * ND * ND, WtL + (size_t)3 * ND * ND,
                    bi_lw, bi_lb, fold_s, linK_s, linV_s,
                    tmp, Y1, Y2, out_single, out_type, key_mask, km2, 1);
}